// Round 10
// baseline (1334.029 us; speedup 1.0000x reference)
//
#include <hip/hip_runtime.h>
#include <hip/hip_fp16.h>
#include <math.h>
#include <stdint.h>

#define Bb 64
#define Nn 4096
#define Uu 64
#define RL 4224                         // 64*66
#define NU (Nn*Uu)
#define MATSZ ((size_t)Nn*(size_t)RL)   // elements per feature matrix
#define ELLW 112                        // ELL row capacity (avg nnz ~42), multiple of 4
#define XSTR 360                        // K-stride (fp16) in gemm LDS, pad of 352

typedef __attribute__((ext_vector_type(8))) short short8;
typedef __attribute__((ext_vector_type(4))) float f32x4;
typedef unsigned int uint;
typedef unsigned short ushort;

__device__ inline ushort f2h(float f){ return __half_as_ushort(__float2half(f)); }
__device__ inline __half2 u2h(uint u){ union{uint v;__half2 h;} c; c.v=u; return c.h; }
__device__ inline uint h2u(__half2 h){ union{__half2 h;uint v;} c; c.h=h; return c.v; }

// ---------------- ELL extraction: entry = {fp16 value duplicated, col}, pad to 4 ----------------
__global__ __launch_bounds__(256) void k_fill(const float* __restrict__ sup,
                                              uint2* __restrict__ pkv, int* __restrict__ rcnt) {
  const int lane = threadIdx.x & 63;
  const int row = blockIdx.x * 4 + (threadIdx.x >> 6);
  const float* rp = sup + (size_t)row * Nn;
  uint2* outp = pkv + (size_t)row * ELLW;
  const unsigned long long lt = (1ull << lane) - 1ull;
  int off = 0;
  for (int j0 = 0; j0 < Nn; j0 += 64) {
    float v = rp[j0 + lane];
    unsigned long long m = __ballot(v != 0.0f);
    if (v != 0.0f) {
      int pos = off + (int)__popcll(m & lt);
      if (pos < ELLW) {
        const uint h = (uint)f2h(v);
        outp[pos] = make_uint2(h | (h << 16), (uint)(j0 + lane));
      }
    }
    off += (int)__popcll(m);
  }
  if (off > ELLW) off = ELLW;
  const int c4 = (off + 3) & ~3;                 // <=112, 112%4==0
  if (lane < c4 - off) outp[off + lane] = make_uint2(0u, 0u);  // av=0: contributes nothing
  if (lane == 0) rcnt[row] = c4;
}

// ---------------- x0 = [inputs | hx] fp16 in [n][b][f], vectorized ----------------
__global__ __launch_bounds__(256) void k_bx0(const float* __restrict__ inp, const float* __restrict__ hx,
                                             ushort* __restrict__ x0) {
  const int n = blockIdx.x;
  const int b = threadIdx.x >> 2, q = threadIdx.x & 3;
  const float* hp = hx + (size_t)b*NU + (size_t)n*Uu + q*16;
  ushort* xp = x0 + (size_t)n*RL + b*66;
  #pragma unroll
  for (int i = 0; i < 4; ++i) {
    const float4 v = *(const float4*)&hp[i*4];
    const int o = 2 + q*16 + i*4;
    *(uint*)&xp[o]     = (uint)f2h(v.x) | ((uint)f2h(v.y) << 16);
    *(uint*)&xp[o + 2] = (uint)f2h(v.z) | ((uint)f2h(v.w) << 16);
  }
  if (q == 0) {
    const float2 iv = *(const float2*)&inp[(size_t)b*(size_t)(Nn*2) + (size_t)n*2];
    *(uint*)&xp[0] = (uint)f2h(iv.x) | ((uint)f2h(iv.y) << 16);
  }
}

// ---------------- one nnz: ds_read_b128 + 4 v_pk_fma_f16, zero unpack ----------------
#define PROC1(AP, COL)                                                  \
  {                                                                     \
    const uint4 w = *(const uint4*)(slb + ((COL) << 4));                \
    const __half2 av = u2h(AP);                                         \
    a01 = __hfma2(av, u2h(w.x), a01);                                   \
    a23 = __hfma2(av, u2h(w.y), a23);                                   \
    a45 = __hfma2(av, u2h(w.z), a45);                                   \
    a67 = __hfma2(av, u2h(w.w), a67);                                   \
  }

// ---------------- SpMM: y = A@x (PASS2: y = 2*A@x - xsub), fp16 ----------------
// Slab = 4096 rows x 8 fp16 cols = 64 KiB -> 2 blocks/CU, 8 waves/SIMD. Natural row
// order, 1 lane per row, ds_read_b128 serves all 8 cols, packed-fp16 MACs.
// Schedule: 512 primary units (XCD-chunked) + 16 leftover units split 128x32.
template<bool PASS2>
__global__ __launch_bounds__(1024, 8) void k_spmm(const ushort* __restrict__ xin,
                                                  const ushort* __restrict__ xsub,
                                                  ushort* __restrict__ yout,
                                                  const int* __restrict__ rcnt,
                                                  const uint2* __restrict__ pkv) {
  __shared__ ushort slab[4096*8];                        // 64 KiB, 16B rows
  const char* slb = (const char*)slab;
  const int t = threadIdx.x, b = blockIdx.x;
  #pragma unroll 1
  for (int task = 0; task < 2; ++task) {
    int unit, r0, nr;
    if (task == 0) { unit = ((b & 7) << 6) + (b >> 3); r0 = 0; nr = 4096; }
    else           { unit = 512 + (b >> 5); r0 = (b & 31) * 128; nr = 128; }
    const int c0 = unit * 8;
    #pragma unroll 1
    for (int s = 0; s < 2; ++s) {
      if (PASS2 || s == 0) {                             // pass1 shares the x slab
        if (task | s) __syncthreads();                   // walkers done before restage
        const ushort* src = xin + (PASS2 ? (size_t)s * MATSZ : (size_t)0) + c0;
        #pragma unroll
        for (int it = 0; it < 4; ++it) {
          const int j = it * 1024 + t;
          *(uint4*)&slab[j * 8] = *(const uint4*)&src[(size_t)j * RL];
        }
        __syncthreads();
      }
      const int sb = s << 12;
      ushort* yo = yout + (size_t)s * MATSZ + c0;
      for (int r = r0 + t; r < r0 + nr; r += 1024) {     // 1 lane per output row
        const int rb = sb + r;
        int p = rb * ELLW;
        const int pe = p + rcnt[rb];
        __half2 a01 = u2h(0), a23 = u2h(0), a45 = u2h(0), a67 = u2h(0);
        for (; p < pe; p += 4) {                         // counts are multiples of 4
          const uint4 e01 = *(const uint4*)&pkv[p];      // entries p, p+1
          const uint4 e23 = *(const uint4*)&pkv[p + 2];  // entries p+2, p+3
          PROC1(e01.x, e01.y);
          PROC1(e01.z, e01.w);
          PROC1(e23.x, e23.y);
          PROC1(e23.z, e23.w);
        }
        uint4 o;
        if (PASS2) {
          const uint4 xv = *(const uint4*)&xsub[(size_t)r*RL + c0];
          o.x = h2u(__hsub2(__hadd2(a01, a01), u2h(xv.x)));
          o.y = h2u(__hsub2(__hadd2(a23, a23), u2h(xv.y)));
          o.z = h2u(__hsub2(__hadd2(a45, a45), u2h(xv.z)));
          o.w = h2u(__hsub2(__hadd2(a67, a67), u2h(xv.w)));
        } else {
          o.x = h2u(a01); o.y = h2u(a23); o.z = h2u(a45); o.w = h2u(a67);
        }
        *(uint4*)&yo[(size_t)r*RL] = o;
      }
    }
  }
}

// ---------------- W pre-pack into MFMA B-fragment order (fp16) ----------------
__global__ __launch_bounds__(256) void k_wpack(const float* __restrict__ W1, const float* __restrict__ W2,
                                               ushort* __restrict__ Wp1, ushort* __restrict__ Wp2) {
  const int tid = blockIdx.x*256 + threadIdx.x;
  const int i = tid & 7, l = (tid >> 3) & 63;
  if (tid < 45056) {
    const int g = tid >> 9, tt = g / 11, kk = g % 11;
    const int r = kk*32 + (l>>4)*8 + i, c = tt*16 + (l & 15);
    Wp1[tid] = (r < 330) ? f2h(W1[(size_t)r*128 + c]) : (ushort)0;
  } else {
    const int t2 = tid - 45056;
    const int g = t2 >> 9, tt = g / 11, kk = g % 11;
    const int r = kk*32 + (l>>4)*8 + i, c = tt*16 + (l & 15);
    Wp2[t2] = (r < 330) ? f2h(W2[(size_t)r*64 + c]) : (ushort)0;
  }
}

// ---------------- gconv1 output GEMM (MFMA f16), fused sigmoid + r*hx + u ----------------
__global__ __launch_bounds__(256) void k_gemm1(const ushort* __restrict__ x0, const ushort* __restrict__ y1,
                                               const ushort* __restrict__ y2, const ushort* __restrict__ Wp,
                                               const float* __restrict__ bias, const float* __restrict__ hx,
                                               ushort* __restrict__ x0w, ushort* __restrict__ ubuf) {
  __shared__ ushort Xs[64*XSTR];                  // [b][k], k = f*5+m, padded to 352
  const int n = blockIdx.x, t = threadIdx.x;
  for (int q = t; q < 64*XSTR/4; q += 256) ((unsigned long long*)Xs)[q] = 0ull;
  __syncthreads();
  for (int m = 0; m < 5; ++m) {
    const ushort* mp;
    if (m == 0) mp = x0; else { mp = (m & 1) ? y1 : y2; if (m >= 3) mp += MATSZ; }
    mp += (size_t)n * RL;
    for (int q = t; q < RL; q += 256) {
      const int b = q / 66, f = q - b*66;
      Xs[b*XSTR + f*5 + m] = mp[q];
    }
  }
  __syncthreads();
  const int w = t >> 6, l = t & 63;
  const int b0 = w * 16;
  f32x4 acc[8];
  for (int i = 0; i < 8; ++i) acc[i] = (f32x4){0.f,0.f,0.f,0.f};
  const int arow = b0 + (l & 15), koff0 = (l >> 4) * 8;
  for (int kk = 0; kk < 11; ++kk) {
    const short8 af = *(const short8*)&Xs[arow*XSTR + kk*32 + koff0];
    #pragma unroll
    for (int tt = 0; tt < 8; ++tt) {
      const short8 bf = *(const short8*)&Wp[(((size_t)tt*11 + kk)*64 + l)*8];
      acc[tt] = __builtin_amdgcn_mfma_f32_16x16x32_f16(af, bf, acc[tt], 0, 0, 0);
    }
  }
  const int rg = (l >> 4) * 4;
  #pragma unroll
  for (int tt = 0; tt < 8; ++tt) {
    const int o = tt*16 + (l & 15);
    const float bs = bias[o];
    #pragma unroll
    for (int r = 0; r < 4; ++r) {
      const int b = b0 + rg + r;
      const float v = acc[tt][r] + bs;
      const float sg = 1.0f / (1.0f + __expf(-v));
      if (o < Uu) {
        const float h = hx[(size_t)b*NU + (size_t)n*Uu + o];
        x0w[(size_t)n*RL + b*66 + 2 + o] = f2h(sg * h);
      } else {
        ubuf[(size_t)b*NU + (size_t)n*Uu + (o - Uu)] = f2h(sg);
      }
    }
  }
}

// ---------------- gconv2 output GEMM (MFMA f16), fused tanh + final gate ----------------
__global__ __launch_bounds__(256) void k_gemm2(const ushort* __restrict__ x0, const ushort* __restrict__ y1,
                                               const ushort* __restrict__ y2, const ushort* __restrict__ Wp,
                                               const float* __restrict__ bias, const float* __restrict__ hx,
                                               const ushort* __restrict__ ubuf, float* __restrict__ out) {
  __shared__ ushort Xs[64*XSTR];
  const int n = blockIdx.x, t = threadIdx.x;
  for (int q = t; q < 64*XSTR/4; q += 256) ((unsigned long long*)Xs)[q] = 0ull;
  __syncthreads();
  for (int m = 0; m < 5; ++m) {
    const ushort* mp;
    if (m == 0) mp = x0; else { mp = (m & 1) ? y1 : y2; if (m >= 3) mp += MATSZ; }
    mp += (size_t)n * RL;
    for (int q = t; q < RL; q += 256) {
      const int b = q / 66, f = q - b*66;
      Xs[b*XSTR + f*5 + m] = mp[q];
    }
  }
  __syncthreads();
  const int w = t >> 6, l = t & 63;
  const int b0 = w * 16;
  f32x4 acc[4];
  for (int i = 0; i < 4; ++i) acc[i] = (f32x4){0.f,0.f,0.f,0.f};
  const int arow = b0 + (l & 15), koff0 = (l >> 4) * 8;
  for (int kk = 0; kk < 11; ++kk) {
    const short8 af = *(const short8*)&Xs[arow*XSTR + kk*32 + koff0];
    #pragma unroll
    for (int tt = 0; tt < 4; ++tt) {
      const short8 bf = *(const short8*)&Wp[(((size_t)tt*11 + kk)*64 + l)*8];
      acc[tt] = __builtin_amdgcn_mfma_f32_16x16x32_f16(af, bf, acc[tt], 0, 0, 0);
    }
  }
  const int rg = (l >> 4) * 4;
  #pragma unroll
  for (int tt = 0; tt < 4; ++tt) {
    const int o = tt*16 + (l & 15);
    const float bs = bias[o];
    #pragma unroll
    for (int r = 0; r < 4; ++r) {
      const int b = b0 + rg + r;
      const float c = tanhf(acc[tt][r] + bs);
      const size_t ix = (size_t)b*NU + (size_t)n*Uu + o;
      const float u = __half2float(__ushort_as_half(ubuf[ix]));
      const float h = hx[ix];
      out[ix] = u*h + (1.0f - u)*c;
    }
  }
}

extern "C" void kernel_launch(void* const* d_in, const int* in_sizes, int n_in,
                              void* d_out, int out_size, void* d_ws, size_t ws_size,
                              hipStream_t stream) {
  const float* inp = (const float*)d_in[0];
  const float* hx  = (const float*)d_in[1];
  const float* sup = (const float*)d_in[2];
  const float* ruW = (const float*)d_in[3];
  const float* ruB = (const float*)d_in[4];
  const float* gW  = (const float*)d_in[5];
  const float* gB  = (const float*)d_in[6];
  float* out = (float*)d_out;

  // workspace (fp16 intermediates, ~215 MB): x0 | y1[2] | y2[2] | u | Wpk | ELL
  ushort* x0   = (ushort*)d_ws;
  ushort* y1   = x0 + MATSZ;
  ushort* y2   = y1 + 2*MATSZ;
  ushort* ubuf = y2 + 2*MATSZ;
  ushort* Wp1  = ubuf + (size_t)Bb*NU;
  ushort* Wp2  = Wp1 + 45056;
  uint2* pkv = (uint2*)(Wp2 + 22528);         // 8192*112 uint2, rows 32B-aligned
  int*  rcnt = (int*)(pkv + (size_t)8192*ELLW);

  k_fill<<<2048, 256, 0, stream>>>(sup, pkv, rcnt);
  k_wpack<<<264, 256, 0, stream>>>(ruW, gW, Wp1, Wp2);
  k_bx0<<<Nn, 256, 0, stream>>>(inp, hx, x0);

  // gconv1
  k_spmm<false><<<512, 1024, 0, stream>>>(x0, nullptr, y1, rcnt, pkv);
  k_spmm<true ><<<512, 1024, 0, stream>>>(y1, x0,      y2, rcnt, pkv);
  k_gemm1<<<Nn, 256, 0, stream>>>(x0, y1, y2, Wp1, ruB, hx, x0, ubuf);
  // gconv2 (x0 state slots now hold fp16(r*hx))
  k_spmm<false><<<512, 1024, 0, stream>>>(x0, nullptr, y1, rcnt, pkv);
  k_spmm<true ><<<512, 1024, 0, stream>>>(y1, x0,      y2, rcnt, pkv);
  k_gemm2<<<Nn, 256, 0, stream>>>(x0, y1, y2, Wp2, gB, hx, ubuf, out);
}

// Round 14
// 1260.770 us; speedup vs baseline: 1.0581x; 1.0581x over previous
//
#include <hip/hip_runtime.h>
#include <hip/hip_fp16.h>
#include <math.h>
#include <stdint.h>

#define Bb 64
#define Nn 4096
#define Uu 64
#define RL 4224                         // 64*66
#define NU (Nn*Uu)
#define MATSZ ((size_t)Nn*(size_t)RL)   // elements per feature matrix
#define ELLW 112                        // ELL row capacity (avg nnz ~42), multiple of 4
#define XSTR 360                        // K-stride (fp16) in gemm LDS, pad of 352

typedef __attribute__((ext_vector_type(8))) short short8;
typedef __attribute__((ext_vector_type(4))) float f32x4;
typedef unsigned int uint;
typedef unsigned short ushort;

__device__ inline ushort f2h(float f){ return __half_as_ushort(__float2half(f)); }
__device__ inline __half2 u2h(uint u){ union{uint v;__half2 h;} c; c.v=u; return c.h; }
__device__ inline uint h2u(__half2 h){ union{__half2 h;uint v;} c; c.h=h; return c.v; }

// ---------------- ELL extraction: entry = (fp16(val)<<16) | (col<<4), pad to 4 ----------------
// addr = e & 0xfff0 (1 op); value broadcast = v_perm (1 op). Pad entries are 0 (val=0).
__global__ __launch_bounds__(256) void k_fill(const float* __restrict__ sup,
                                              uint* __restrict__ pkv, int* __restrict__ rcnt) {
  const int lane = threadIdx.x & 63;
  const int row = blockIdx.x * 4 + (threadIdx.x >> 6);
  const float* rp = sup + (size_t)row * Nn;
  uint* outp = pkv + (size_t)row * ELLW;
  const unsigned long long lt = (1ull << lane) - 1ull;
  int off = 0;
  for (int j0 = 0; j0 < Nn; j0 += 64) {
    float v = rp[j0 + lane];
    unsigned long long m = __ballot(v != 0.0f);
    if (v != 0.0f) {
      int pos = off + (int)__popcll(m & lt);
      if (pos < ELLW) outp[pos] = ((uint)f2h(v) << 16) | ((uint)(j0 + lane) << 4);
    }
    off += (int)__popcll(m);
  }
  if (off > ELLW) off = ELLW;
  const int c4 = (off + 3) & ~3;                 // <=112, 112%4==0
  if (lane < c4 - off) outp[off + lane] = 0u;    // val=0: contributes nothing
  if (lane == 0) rcnt[row] = c4;
}

// ---------------- x0 = [inputs | hx] fp16 in [n][b][f], vectorized ----------------
__global__ __launch_bounds__(256) void k_bx0(const float* __restrict__ inp, const float* __restrict__ hx,
                                             ushort* __restrict__ x0) {
  const int n = blockIdx.x;
  const int b = threadIdx.x >> 2, q = threadIdx.x & 3;
  const float* hp = hx + (size_t)b*NU + (size_t)n*Uu + q*16;
  ushort* xp = x0 + (size_t)n*RL + b*66;
  #pragma unroll
  for (int i = 0; i < 4; ++i) {
    const float4 v = *(const float4*)&hp[i*4];
    const int o = 2 + q*16 + i*4;
    *(uint*)&xp[o]     = (uint)f2h(v.x) | ((uint)f2h(v.y) << 16);
    *(uint*)&xp[o + 2] = (uint)f2h(v.z) | ((uint)f2h(v.w) << 16);
  }
  if (q == 0) {
    const float2 iv = *(const float2*)&inp[(size_t)b*(size_t)(Nn*2) + (size_t)n*2];
    *(uint*)&xp[0] = (uint)f2h(iv.x) | ((uint)f2h(iv.y) << 16);
  }
}

// ---------------- 4 entries: 4 ds_read_b128 issued together, then 16 v_pk_fma_f16 ----------------
#define PROC4(E)                                                                   \
  {                                                                                \
    const uint4 w0 = *(const uint4*)(slb + (E.x & 0xfff0u));                       \
    const uint4 w1 = *(const uint4*)(slb + (E.y & 0xfff0u));                       \
    const uint4 w2 = *(const uint4*)(slb + (E.z & 0xfff0u));                       \
    const uint4 w3 = *(const uint4*)(slb + (E.w & 0xfff0u));                       \
    const __half2 av0 = u2h(__builtin_amdgcn_perm(E.x, E.x, 0x03020302u));         \
    const __half2 av1 = u2h(__builtin_amdgcn_perm(E.y, E.y, 0x03020302u));         \
    const __half2 av2 = u2h(__builtin_amdgcn_perm(E.z, E.z, 0x03020302u));         \
    const __half2 av3 = u2h(__builtin_amdgcn_perm(E.w, E.w, 0x03020302u));         \
    a01 = __hfma2(av0, u2h(w0.x), a01); a23 = __hfma2(av0, u2h(w0.y), a23);        \
    a45 = __hfma2(av0, u2h(w0.z), a45); a67 = __hfma2(av0, u2h(w0.w), a67);        \
    a01 = __hfma2(av1, u2h(w1.x), a01); a23 = __hfma2(av1, u2h(w1.y), a23);        \
    a45 = __hfma2(av1, u2h(w1.z), a45); a67 = __hfma2(av1, u2h(w1.w), a67);        \
    a01 = __hfma2(av2, u2h(w2.x), a01); a23 = __hfma2(av2, u2h(w2.y), a23);        \
    a45 = __hfma2(av2, u2h(w2.z), a45); a67 = __hfma2(av2, u2h(w2.w), a67);        \
    a01 = __hfma2(av3, u2h(w3.x), a01); a23 = __hfma2(av3, u2h(w3.y), a23);        \
    a45 = __hfma2(av3, u2h(w3.z), a45); a67 = __hfma2(av3, u2h(w3.w), a67);        \
  }

// ---------------- SpMM: y = A@x (PASS2: y = 2*A@x - xsub), fp16, 4B entries ----------------
// Slab = 4096 rows x 8 fp16 cols = 64 KiB -> 2 blocks/CU, 8 waves/SIMD. Natural row
// order, 1 lane per row, ds_read_b128 serves 8 cols. e-loads: 1 uint4 per 4 entries,
// software-pipelined (next batch loads before current batch's FMAs).
// Schedule: 512 primary units (XCD-chunked) + 16 leftover units split 128x32.
template<bool PASS2>
__global__ __launch_bounds__(1024, 8) void k_spmm(const ushort* __restrict__ xin,
                                                  const ushort* __restrict__ xsub,
                                                  ushort* __restrict__ yout,
                                                  const int* __restrict__ rcnt,
                                                  const uint* __restrict__ pkv) {
  __shared__ ushort slab[4096*8];                        // 64 KiB, 16B rows
  const char* slb = (const char*)slab;
  const int t = threadIdx.x, b = blockIdx.x;
  #pragma unroll 1
  for (int task = 0; task < 2; ++task) {
    int unit, r0, nr;
    if (task == 0) { unit = ((b & 7) << 6) + (b >> 3); r0 = 0; nr = 4096; }
    else           { unit = 512 + (b >> 5); r0 = (b & 31) * 128; nr = 128; }
    const int c0 = unit * 8;
    #pragma unroll 1
    for (int s = 0; s < 2; ++s) {
      if (PASS2 || s == 0) {                             // pass1 shares the x slab
        if (task | s) __syncthreads();                   // walkers done before restage
        const ushort* src = xin + (PASS2 ? (size_t)s * MATSZ : (size_t)0) + c0;
        #pragma unroll
        for (int it = 0; it < 4; ++it) {
          const int j = it * 1024 + t;
          *(uint4*)&slab[j * 8] = *(const uint4*)&src[(size_t)j * RL];
        }
        __syncthreads();
      }
      const int sb = s << 12;
      ushort* yo = yout + (size_t)s * MATSZ + c0;
      for (int r = r0 + t; r < r0 + nr; r += 1024) {     // 1 lane per output row
        const int rb = sb + r;
        int p = rb * ELLW;
        const int pe = p + rcnt[rb];                     // count >= 4, multiple of 4
        __half2 a01 = u2h(0), a23 = u2h(0), a45 = u2h(0), a67 = u2h(0);
        uint4 e = *(const uint4*)&pkv[p];
        for (p += 4; p < pe; p += 4) {                   // prefetch next batch
          const uint4 en = *(const uint4*)&pkv[p];
          PROC4(e);
          e = en;
        }
        PROC4(e);
        uint4 o;
        if (PASS2) {
          const uint4 xv = *(const uint4*)&xsub[(size_t)r*RL + c0];
          o.x = h2u(__hsub2(__hadd2(a01, a01), u2h(xv.x)));
          o.y = h2u(__hsub2(__hadd2(a23, a23), u2h(xv.y)));
          o.z = h2u(__hsub2(__hadd2(a45, a45), u2h(xv.z)));
          o.w = h2u(__hsub2(__hadd2(a67, a67), u2h(xv.w)));
        } else {
          o.x = h2u(a01); o.y = h2u(a23); o.z = h2u(a45); o.w = h2u(a67);
        }
        *(uint4*)&yo[(size_t)r*RL] = o;
      }
    }
  }
}

// ---------------- W pre-pack into MFMA B-fragment order (fp16) ----------------
__global__ __launch_bounds__(256) void k_wpack(const float* __restrict__ W1, const float* __restrict__ W2,
                                               ushort* __restrict__ Wp1, ushort* __restrict__ Wp2) {
  const int tid = blockIdx.x*256 + threadIdx.x;
  const int i = tid & 7, l = (tid >> 3) & 63;
  if (tid < 45056) {
    const int g = tid >> 9, tt = g / 11, kk = g % 11;
    const int r = kk*32 + (l>>4)*8 + i, c = tt*16 + (l & 15);
    Wp1[tid] = (r < 330) ? f2h(W1[(size_t)r*128 + c]) : (ushort)0;
  } else {
    const int t2 = tid - 45056;
    const int g = t2 >> 9, tt = g / 11, kk = g % 11;
    const int r = kk*32 + (l>>4)*8 + i, c = tt*16 + (l & 15);
    Wp2[t2] = (r < 330) ? f2h(W2[(size_t)r*64 + c]) : (ushort)0;
  }
}

// ---------------- gconv1 output GEMM (MFMA f16), fused sigmoid + r*hx + u ----------------
__global__ __launch_bounds__(256) void k_gemm1(const ushort* __restrict__ x0, const ushort* __restrict__ y1,
                                               const ushort* __restrict__ y2, const ushort* __restrict__ Wp,
                                               const float* __restrict__ bias, const float* __restrict__ hx,
                                               ushort* __restrict__ x0w, ushort* __restrict__ ubuf) {
  __shared__ ushort Xs[64*XSTR];                  // [b][k], k = f*5+m, padded to 352
  const int n = blockIdx.x, t = threadIdx.x;
  for (int q = t; q < 64*XSTR/4; q += 256) ((unsigned long long*)Xs)[q] = 0ull;
  __syncthreads();
  for (int m = 0; m < 5; ++m) {
    const ushort* mp;
    if (m == 0) mp = x0; else { mp = (m & 1) ? y1 : y2; if (m >= 3) mp += MATSZ; }
    mp += (size_t)n * RL;
    for (int q = t; q < RL; q += 256) {
      const int b = q / 66, f = q - b*66;
      Xs[b*XSTR + f*5 + m] = mp[q];
    }
  }
  __syncthreads();
  const int w = t >> 6, l = t & 63;
  const int b0 = w * 16;
  f32x4 acc[8];
  for (int i = 0; i < 8; ++i) acc[i] = (f32x4){0.f,0.f,0.f,0.f};
  const int arow = b0 + (l & 15), koff0 = (l >> 4) * 8;
  for (int kk = 0; kk < 11; ++kk) {
    const short8 af = *(const short8*)&Xs[arow*XSTR + kk*32 + koff0];
    #pragma unroll
    for (int tt = 0; tt < 8; ++tt) {
      const short8 bf = *(const short8*)&Wp[(((size_t)tt*11 + kk)*64 + l)*8];
      acc[tt] = __builtin_amdgcn_mfma_f32_16x16x32_f16(af, bf, acc[tt], 0, 0, 0);
    }
  }
  const int rg = (l >> 4) * 4;
  #pragma unroll
  for (int tt = 0; tt < 8; ++tt) {
    const int o = tt*16 + (l & 15);
    const float bs = bias[o];
    #pragma unroll
    for (int r = 0; r < 4; ++r) {
      const int b = b0 + rg + r;
      const float v = acc[tt][r] + bs;
      const float sg = 1.0f / (1.0f + __expf(-v));
      if (o < Uu) {
        const float h = hx[(size_t)b*NU + (size_t)n*Uu + o];
        x0w[(size_t)n*RL + b*66 + 2 + o] = f2h(sg * h);
      } else {
        ubuf[(size_t)b*NU + (size_t)n*Uu + (o - Uu)] = f2h(sg);
      }
    }
  }
}

// ---------------- gconv2 output GEMM (MFMA f16), fused tanh + final gate ----------------
__global__ __launch_bounds__(256) void k_gemm2(const ushort* __restrict__ x0, const ushort* __restrict__ y1,
                                               const ushort* __restrict__ y2, const ushort* __restrict__ Wp,
                                               const float* __restrict__ bias, const float* __restrict__ hx,
                                               const ushort* __restrict__ ubuf, float* __restrict__ out) {
  __shared__ ushort Xs[64*XSTR];
  const int n = blockIdx.x, t = threadIdx.x;
  for (int q = t; q < 64*XSTR/4; q += 256) ((unsigned long long*)Xs)[q] = 0ull;
  __syncthreads();
  for (int m = 0; m < 5; ++m) {
    const ushort* mp;
    if (m == 0) mp = x0; else { mp = (m & 1) ? y1 : y2; if (m >= 3) mp += MATSZ; }
    mp += (size_t)n * RL;
    for (int q = t; q < RL; q += 256) {
      const int b = q / 66, f = q - b*66;
      Xs[b*XSTR + f*5 + m] = mp[q];
    }
  }
  __syncthreads();
  const int w = t >> 6, l = t & 63;
  const int b0 = w * 16;
  f32x4 acc[4];
  for (int i = 0; i < 4; ++i) acc[i] = (f32x4){0.f,0.f,0.f,0.f};
  const int arow = b0 + (l & 15), koff0 = (l >> 4) * 8;
  for (int kk = 0; kk < 11; ++kk) {
    const short8 af = *(const short8*)&Xs[arow*XSTR + kk*32 + koff0];
    #pragma unroll
    for (int tt = 0; tt < 4; ++tt) {
      const short8 bf = *(const short8*)&Wp[(((size_t)tt*11 + kk)*64 + l)*8];
      acc[tt] = __builtin_amdgcn_mfma_f32_16x16x32_f16(af, bf, acc[tt], 0, 0, 0);
    }
  }
  const int rg = (l >> 4) * 4;
  #pragma unroll
  for (int tt = 0; tt < 4; ++tt) {
    const int o = tt*16 + (l & 15);
    const float bs = bias[o];
    #pragma unroll
    for (int r = 0; r < 4; ++r) {
      const int b = b0 + rg + r;
      const float c = tanhf(acc[tt][r] + bs);
      const size_t ix = (size_t)b*NU + (size_t)n*Uu + o;
      const float u = __half2float(__ushort_as_half(ubuf[ix]));
      const float h = hx[ix];
      out[ix] = u*h + (1.0f - u)*c;
    }
  }
}

extern "C" void kernel_launch(void* const* d_in, const int* in_sizes, int n_in,
                              void* d_out, int out_size, void* d_ws, size_t ws_size,
                              hipStream_t stream) {
  const float* inp = (const float*)d_in[0];
  const float* hx  = (const float*)d_in[1];
  const float* sup = (const float*)d_in[2];
  const float* ruW = (const float*)d_in[3];
  const float* ruB = (const float*)d_in[4];
  const float* gW  = (const float*)d_in[5];
  const float* gB  = (const float*)d_in[6];
  float* out = (float*)d_out;

  // workspace (fp16 intermediates, ~215 MB): x0 | y1[2] | y2[2] | u | Wpk | ELL
  ushort* x0   = (ushort*)d_ws;
  ushort* y1   = x0 + MATSZ;
  ushort* y2   = y1 + 2*MATSZ;
  ushort* ubuf = y2 + 2*MATSZ;
  ushort* Wp1  = ubuf + (size_t)Bb*NU;
  ushort* Wp2  = Wp1 + 45056;
  uint* pkv  = (uint*)(Wp2 + 22528);          // 8192*112 uints, rows 16B-aligned
  int*  rcnt = (int*)(pkv + (size_t)8192*ELLW);

  k_fill<<<2048, 256, 0, stream>>>(sup, pkv, rcnt);
  k_wpack<<<264, 256, 0, stream>>>(ruW, gW, Wp1, Wp2);
  k_bx0<<<Nn, 256, 0, stream>>>(inp, hx, x0);

  // gconv1
  k_spmm<false><<<512, 1024, 0, stream>>>(x0, nullptr, y1, rcnt, pkv);
  k_spmm<true ><<<512, 1024, 0, stream>>>(y1, x0,      y2, rcnt, pkv);
  k_gemm1<<<Nn, 256, 0, stream>>>(x0, y1, y2, Wp1, ruB, hx, x0, ubuf);
  // gconv2 (x0 state slots now hold fp16(r*hx))
  k_spmm<false><<<512, 1024, 0, stream>>>(x0, nullptr, y1, rcnt, pkv);
  k_spmm<true ><<<512, 1024, 0, stream>>>(y1, x0,      y2, rcnt, pkv);
  k_gemm2<<<Nn, 256, 0, stream>>>(x0, y1, y2, Wp2, gB, hx, ubuf, out);
}

// Round 15
// 1021.012 us; speedup vs baseline: 1.3066x; 1.2348x over previous
//
#include <hip/hip_runtime.h>
#include <math.h>
#include <stdint.h>

#define Bb 64
#define Nn 4096
#define Uu 64
#define RL 4224                         // 64*66
#define NU (Nn*Uu)
#define MATSZ ((size_t)Nn*(size_t)RL)   // elements per feature matrix
#define ELLW 112                        // ELL row capacity (avg nnz ~42), multiple of 4
#define XSTR 360                        // K-stride (bf16) in gemm LDS, pad of 352

typedef __attribute__((ext_vector_type(8))) short short8;
typedef __attribute__((ext_vector_type(4))) float f32x4;
typedef unsigned int uint;
typedef unsigned short ushort;

__device__ inline uint f2bf(float f){ uint u=__float_as_uint(f); u += 0x7fffu + ((u>>16)&1u); return u>>16; }
__device__ inline uint pack2(float a,float b){
  uint ua=__float_as_uint(a); ua+=0x7fffu+((ua>>16)&1u);
  uint ub=__float_as_uint(b); ub+=0x7fffu+((ub>>16)&1u);
  return (ua>>16)|(ub&0xffff0000u);
}
__device__ inline float blo(uint u){ return __uint_as_float(u << 16); }
__device__ inline float bhi(uint u){ return __uint_as_float(u & 0xffff0000u); }

// ---------------- ELL extraction (row-major), counts padded to multiples of 4 ----------------
// entry = (bf16(val)<<16) | col ; zero-pad entries contribute nothing
__global__ __launch_bounds__(256) void k_fill(const float* __restrict__ sup,
                                              uint* __restrict__ pkv, int* __restrict__ rcnt) {
  const int lane = threadIdx.x & 63;
  const int row = blockIdx.x * 4 + (threadIdx.x >> 6);
  const float* rp = sup + (size_t)row * Nn;
  uint* outp = pkv + (size_t)row * ELLW;
  const unsigned long long lt = (1ull << lane) - 1ull;
  int off = 0;
  for (int j0 = 0; j0 < Nn; j0 += 64) {
    float v = rp[j0 + lane];
    unsigned long long m = __ballot(v != 0.0f);
    if (v != 0.0f) {
      int pos = off + (int)__popcll(m & lt);
      if (pos < ELLW) outp[pos] = (f2bf(v) << 16) | (uint)(j0 + lane);
    }
    off += (int)__popcll(m);
  }
  if (off > ELLW) off = ELLW;
  const int c4 = (off + 3) & ~3;                 // <=112, 112%4==0
  if (lane < c4 - off) outp[off + lane] = 0u;
  if (lane == 0) rcnt[row] = c4;
}

// ---------------- ELL transpose -> column-major pT[i][8192] ----------------
// Walk e-loads become 256B coalesced wave-loads (was 64 cache lines per wave-load).
__global__ __launch_bounds__(256) void k_tr(const uint* __restrict__ pkv, uint* __restrict__ pT) {
  __shared__ uint tile[64*113];                  // stride 113: odd vs 32 banks
  const int g = blockIdx.x, t = threadIdx.x;     // 128 blocks x 64 rows
  const uint* src = pkv + (size_t)g * 64 * ELLW;
  for (int idx = t; idx < 64*ELLW; idx += 256) {
    const int r = idx / ELLW, i = idx - r*ELLW;
    tile[r*113 + i] = src[idx];
  }
  __syncthreads();
  for (int idx = t; idx < 64*ELLW; idx += 256) {
    const int i = idx >> 6, r = idx & 63;
    pT[(size_t)i*8192 + g*64 + r] = tile[r*113 + i];
  }
}

// ---------------- x0 = [inputs | hx] bf16 in [n][b][f], vectorized ----------------
__global__ __launch_bounds__(256) void k_bx0(const float* __restrict__ inp, const float* __restrict__ hx,
                                             ushort* __restrict__ x0) {
  const int n = blockIdx.x;
  const int b = threadIdx.x >> 2, q = threadIdx.x & 3;
  const float* hp = hx + (size_t)b*NU + (size_t)n*Uu + q*16;
  ushort* xp = x0 + (size_t)n*RL + b*66;
  #pragma unroll
  for (int i = 0; i < 4; ++i) {
    const float4 v = *(const float4*)&hp[i*4];
    const int o = 2 + q*16 + i*4;
    *(uint*)&xp[o]     = pack2(v.x, v.y);
    *(uint*)&xp[o + 2] = pack2(v.z, v.w);
  }
  if (q == 0) {
    const float2 iv = *(const float2*)&inp[(size_t)b*(size_t)(Nn*2) + (size_t)n*2];
    *(uint*)&xp[0] = pack2(iv.x, iv.y);
  }
}

// ---------------- 4 entries: 4 ds_read_b128 + FMAs (R8-identical math) ----------------
#define PROC4(EA, EB, EC, ED)                                                         \
  {                                                                                   \
    const uint4 w0 = *(const uint4*)(slb + ((EA << 4) & 0xffff0u));                   \
    const uint4 w1 = *(const uint4*)(slb + ((EB << 4) & 0xffff0u));                   \
    const uint4 w2 = *(const uint4*)(slb + ((EC << 4) & 0xffff0u));                   \
    const uint4 w3 = *(const uint4*)(slb + ((ED << 4) & 0xffff0u));                   \
    const float b0 = bhi(EA), b1 = bhi(EB), b2 = bhi(EC), b3 = bhi(ED);               \
    a0 += b0*blo(w0.x); a1 += b0*bhi(w0.x); a2 += b0*blo(w0.y); a3 += b0*bhi(w0.y);   \
    a4 += b0*blo(w0.z); a5 += b0*bhi(w0.z); a6 += b0*blo(w0.w); a7 += b0*bhi(w0.w);   \
    a0 += b1*blo(w1.x); a1 += b1*bhi(w1.x); a2 += b1*blo(w1.y); a3 += b1*bhi(w1.y);   \
    a4 += b1*blo(w1.z); a5 += b1*bhi(w1.z); a6 += b1*blo(w1.w); a7 += b1*bhi(w1.w);   \
    a0 += b2*blo(w2.x); a1 += b2*bhi(w2.x); a2 += b2*blo(w2.y); a3 += b2*bhi(w2.y);   \
    a4 += b2*blo(w2.z); a5 += b2*bhi(w2.z); a6 += b2*blo(w2.w); a7 += b2*bhi(w2.w);   \
    a0 += b3*blo(w3.x); a1 += b3*bhi(w3.x); a2 += b3*blo(w3.y); a3 += b3*bhi(w3.y);   \
    a4 += b3*blo(w3.z); a5 += b3*bhi(w3.z); a6 += b3*blo(w3.w); a7 += b3*bhi(w3.w);   \
  }

// ---------------- SpMM: y = A@x (PASS2: y = 2*A@x - xsub) ----------------
// R8 structure: 64 KiB slab (4096 rows x 8 bf16 cols), 2 blocks/CU, 8 waves/SIMD,
// natural row order, 1 lane/row, ds_read_b128 serves 8 cols.
// ONLY change vs R8: e-loads via column-major pT -> each batch = 4 coalesced 256B
// wave-loads (lane r reads pT[i*8192 + row r]) instead of a 64-line uint4 gather.
// Next batch prefetched -> 8 independent loads in flight.
template<bool PASS2>
__global__ __launch_bounds__(1024, 8) void k_spmm(const ushort* __restrict__ xin,
                                                  const ushort* __restrict__ xsub,
                                                  ushort* __restrict__ yout,
                                                  const int* __restrict__ rcnt,
                                                  const uint* __restrict__ pT) {
  __shared__ ushort slab[4096*8];                        // 64 KiB, 16B rows
  const char* slb = (const char*)slab;
  const int t = threadIdx.x, b = blockIdx.x;
  #pragma unroll 1
  for (int task = 0; task < 2; ++task) {
    int unit, r0, nr;
    if (task == 0) { unit = ((b & 7) << 6) + (b >> 3); r0 = 0; nr = 4096; }
    else           { unit = 512 + (b >> 5); r0 = (b & 31) * 128; nr = 128; }
    const int c0 = unit * 8;
    #pragma unroll 1
    for (int s = 0; s < 2; ++s) {
      if (PASS2 || s == 0) {                             // pass1 shares the x slab
        if (task | s) __syncthreads();                   // walkers done before restage
        const ushort* src = xin + (PASS2 ? (size_t)s * MATSZ : (size_t)0) + c0;
        #pragma unroll
        for (int it = 0; it < 4; ++it) {
          const int j = it * 1024 + t;
          *(uint4*)&slab[j * 8] = *(const uint4*)&src[(size_t)j * RL];
        }
        __syncthreads();
      }
      const int sb = s << 12;
      ushort* yo = yout + (size_t)s * MATSZ + c0;
      for (int r = r0 + t; r < r0 + nr; r += 1024) {     // 1 lane per output row
        const int rb = sb + r;
        const int c = rcnt[rb];                          // multiple of 4, >= 4
        const uint* pp = pT + rb;                        // entry i at pp[i*8192]
        float a0=0.f,a1=0.f,a2=0.f,a3=0.f,a4=0.f,a5=0.f,a6=0.f,a7=0.f;
        uint e0 = pp[0], e1 = pp[8192], e2 = pp[16384], e3 = pp[24576];
        pp += 32768;
        for (int i = 4; i < c; i += 4) {                 // prefetch next 4 columns
          const uint f0 = pp[0], f1 = pp[8192], f2 = pp[16384], f3 = pp[24576];
          pp += 32768;
          PROC4(e0, e1, e2, e3);
          e0 = f0; e1 = f1; e2 = f2; e3 = f3;
        }
        PROC4(e0, e1, e2, e3);
        uint4 o;
        if (PASS2) {
          const uint4 xv = *(const uint4*)&xsub[(size_t)r*RL + c0];
          o.x = pack2(2.f*a0 - blo(xv.x), 2.f*a1 - bhi(xv.x));
          o.y = pack2(2.f*a2 - blo(xv.y), 2.f*a3 - bhi(xv.y));
          o.z = pack2(2.f*a4 - blo(xv.z), 2.f*a5 - bhi(xv.z));
          o.w = pack2(2.f*a6 - blo(xv.w), 2.f*a7 - bhi(xv.w));
        } else {
          o.x = pack2(a0,a1); o.y = pack2(a2,a3); o.z = pack2(a4,a5); o.w = pack2(a6,a7);
        }
        *(uint4*)&yo[(size_t)r*RL] = o;
      }
    }
  }
}

// ---------------- W pre-pack into MFMA B-fragment order (bf16) ----------------
__global__ __launch_bounds__(256) void k_wpack(const float* __restrict__ W1, const float* __restrict__ W2,
                                               ushort* __restrict__ Wp1, ushort* __restrict__ Wp2) {
  const int tid = blockIdx.x*256 + threadIdx.x;
  const int i = tid & 7, l = (tid >> 3) & 63;
  if (tid < 45056) {
    const int g = tid >> 9, tt = g / 11, kk = g % 11;
    const int r = kk*32 + (l>>4)*8 + i, c = tt*16 + (l & 15);
    Wp1[tid] = (r < 330) ? (ushort)f2bf(W1[(size_t)r*128 + c]) : (ushort)0;
  } else {
    const int t2 = tid - 45056;
    const int g = t2 >> 9, tt = g / 11, kk = g % 11;
    const int r = kk*32 + (l>>4)*8 + i, c = tt*16 + (l & 15);
    Wp2[t2] = (r < 330) ? (ushort)f2bf(W2[(size_t)r*64 + c]) : (ushort)0;
  }
}

// ---------------- gconv1 output GEMM (MFMA bf16), fused sigmoid + r*hx + u ----------------
__global__ __launch_bounds__(256) void k_gemm1(const ushort* __restrict__ x0, const ushort* __restrict__ y1,
                                               const ushort* __restrict__ y2, const ushort* __restrict__ Wp,
                                               const float* __restrict__ bias, const float* __restrict__ hx,
                                               ushort* __restrict__ x0w, ushort* __restrict__ ubuf) {
  __shared__ ushort Xs[64*XSTR];
  const int n = blockIdx.x, t = threadIdx.x;
  for (int q = t; q < 64*XSTR/4; q += 256) ((unsigned long long*)Xs)[q] = 0ull;
  __syncthreads();
  for (int m = 0; m < 5; ++m) {
    const ushort* mp;
    if (m == 0) mp = x0; else { mp = (m & 1) ? y1 : y2; if (m >= 3) mp += MATSZ; }
    mp += (size_t)n * RL;
    for (int q = t; q < RL; q += 256) {
      const int b = q / 66, f = q - b*66;
      Xs[b*XSTR + f*5 + m] = mp[q];
    }
  }
  __syncthreads();
  const int w = t >> 6, l = t & 63;
  const int b0 = w * 16;
  f32x4 acc[8];
  for (int i = 0; i < 8; ++i) acc[i] = (f32x4){0.f,0.f,0.f,0.f};
  const int arow = b0 + (l & 15), koff0 = (l >> 4) * 8;
  for (int kk = 0; kk < 11; ++kk) {
    const short8 af = *(const short8*)&Xs[arow*XSTR + kk*32 + koff0];
    #pragma unroll
    for (int tt = 0; tt < 8; ++tt) {
      const short8 bf = *(const short8*)&Wp[(((size_t)tt*11 + kk)*64 + l)*8];
      acc[tt] = __builtin_amdgcn_mfma_f32_16x16x32_bf16(af, bf, acc[tt], 0, 0, 0);
    }
  }
  const int rg = (l >> 4) * 4;
  #pragma unroll
  for (int tt = 0; tt < 8; ++tt) {
    const int o = tt*16 + (l & 15);
    const float bs = bias[o];
    #pragma unroll
    for (int r = 0; r < 4; ++r) {
      const int b = b0 + rg + r;
      const float v = acc[tt][r] + bs;
      const float sg = 1.0f / (1.0f + __expf(-v));
      if (o < Uu) {
        const float h = hx[(size_t)b*NU + (size_t)n*Uu + o];
        x0w[(size_t)n*RL + b*66 + 2 + o] = (ushort)f2bf(sg * h);
      } else {
        ubuf[(size_t)b*NU + (size_t)n*Uu + (o - Uu)] = (ushort)f2bf(sg);
      }
    }
  }
}

// ---------------- gconv2 output GEMM (MFMA bf16), fused tanh + final gate ----------------
__global__ __launch_bounds__(256) void k_gemm2(const ushort* __restrict__ x0, const ushort* __restrict__ y1,
                                               const ushort* __restrict__ y2, const ushort* __restrict__ Wp,
                                               const float* __restrict__ bias, const float* __restrict__ hx,
                                               const ushort* __restrict__ ubuf, float* __restrict__ out) {
  __shared__ ushort Xs[64*XSTR];
  const int n = blockIdx.x, t = threadIdx.x;
  for (int q = t; q < 64*XSTR/4; q += 256) ((unsigned long long*)Xs)[q] = 0ull;
  __syncthreads();
  for (int m = 0; m < 5; ++m) {
    const ushort* mp;
    if (m == 0) mp = x0; else { mp = (m & 1) ? y1 : y2; if (m >= 3) mp += MATSZ; }
    mp += (size_t)n * RL;
    for (int q = t; q < RL; q += 256) {
      const int b = q / 66, f = q - b*66;
      Xs[b*XSTR + f*5 + m] = mp[q];
    }
  }
  __syncthreads();
  const int w = t >> 6, l = t & 63;
  const int b0 = w * 16;
  f32x4 acc[4];
  for (int i = 0; i < 4; ++i) acc[i] = (f32x4){0.f,0.f,0.f,0.f};
  const int arow = b0 + (l & 15), koff0 = (l >> 4) * 8;
  for (int kk = 0; kk < 11; ++kk) {
    const short8 af = *(const short8*)&Xs[arow*XSTR + kk*32 + koff0];
    #pragma unroll
    for (int tt = 0; tt < 4; ++tt) {
      const short8 bf = *(const short8*)&Wp[(((size_t)tt*11 + kk)*64 + l)*8];
      acc[tt] = __builtin_amdgcn_mfma_f32_16x16x32_bf16(af, bf, acc[tt], 0, 0, 0);
    }
  }
  const int rg = (l >> 4) * 4;
  #pragma unroll
  for (int tt = 0; tt < 4; ++tt) {
    const int o = tt*16 + (l & 15);
    const float bs = bias[o];
    #pragma unroll
    for (int r = 0; r < 4; ++r) {
      const int b = b0 + rg + r;
      const float c = tanhf(acc[tt][r] + bs);
      const size_t ix = (size_t)b*NU + (size_t)n*Uu + o;
      const float u = __uint_as_float(((uint)ubuf[ix]) << 16);
      const float h = hx[ix];
      out[ix] = u*h + (1.0f - u)*c;
    }
  }
}

extern "C" void kernel_launch(void* const* d_in, const int* in_sizes, int n_in,
                              void* d_out, int out_size, void* d_ws, size_t ws_size,
                              hipStream_t stream) {
  const float* inp = (const float*)d_in[0];
  const float* hx  = (const float*)d_in[1];
  const float* sup = (const float*)d_in[2];
  const float* ruW = (const float*)d_in[3];
  const float* ruB = (const float*)d_in[4];
  const float* gW  = (const float*)d_in[5];
  const float* gB  = (const float*)d_in[6];
  float* out = (float*)d_out;

  // workspace: x0 | y1[2] | y2[2] | u | Wpk | ELL(row) | ELL(col) | rcnt  (~215 MB)
  ushort* x0   = (ushort*)d_ws;
  ushort* y1   = x0 + MATSZ;
  ushort* y2   = y1 + 2*MATSZ;
  ushort* ubuf = y2 + 2*MATSZ;
  ushort* Wp1  = ubuf + (size_t)Bb*NU;
  ushort* Wp2  = Wp1 + 45056;
  uint* pkv  = (uint*)(Wp2 + 22528);
  uint* pT   = pkv + (size_t)8192*ELLW;
  int*  rcnt = (int*)(pT + (size_t)8192*ELLW);

  k_fill<<<2048, 256, 0, stream>>>(sup, pkv, rcnt);
  k_tr<<<128, 256, 0, stream>>>(pkv, pT);
  k_wpack<<<264, 256, 0, stream>>>(ruW, gW, Wp1, Wp2);
  k_bx0<<<Nn, 256, 0, stream>>>(inp, hx, x0);

  // gconv1
  k_spmm<false><<<512, 1024, 0, stream>>>(x0, nullptr, y1, rcnt, pT);
  k_spmm<true ><<<512, 1024, 0, stream>>>(y1, x0,      y2, rcnt, pT);
  k_gemm1<<<Nn, 256, 0, stream>>>(x0, y1, y2, Wp1, ruB, hx, x0, ubuf);
  // gconv2 (x0 state slots now hold bf16(r*hx))
  k_spmm<false><<<512, 1024, 0, stream>>>(x0, nullptr, y1, rcnt, pT);
  k_spmm<true ><<<512, 1024, 0, stream>>>(y1, x0,      y2, rcnt, pT);
  k_gemm2<<<Nn, 256, 0, stream>>>(x0, y1, y2, Wp2, gB, hx, ubuf, out);
}

// Round 16
// 813.058 us; speedup vs baseline: 1.6408x; 1.2558x over previous
//
#include <hip/hip_runtime.h>
#include <hip/hip_fp16.h>
#include <math.h>
#include <stdint.h>

#define Bb 64
#define Nn 4096
#define Uu 64
#define RL 4224                         // 64*66
#define NU (Nn*Uu)
#define MATSZ ((size_t)Nn*(size_t)RL)   // elements per feature matrix
#define ELLW 112                        // ELL row capacity (avg nnz ~42), multiple of 4
#define XSTR 360                        // K-stride (fp16) in gemm LDS, pad of 352

typedef __attribute__((ext_vector_type(8))) short short8;
typedef __attribute__((ext_vector_type(4))) float f32x4;
typedef unsigned int uint;
typedef unsigned short ushort;

__device__ inline ushort f2h(float f){ return __half_as_ushort(__float2half(f)); }
__device__ inline __half2 u2h(uint u){ union{uint v;__half2 h;} c; c.v=u; return c.h; }
__device__ inline uint h2u(__half2 h){ union{__half2 h;uint v;} c; c.h=h; return c.v; }

// ---------------- ELL extraction: entry = (fp16(val)<<16) | (col<<4), pad to 4 ----------------
__global__ __launch_bounds__(256) void k_fill(const float* __restrict__ sup,
                                              uint* __restrict__ pkv, int* __restrict__ rcnt) {
  const int lane = threadIdx.x & 63;
  const int row = blockIdx.x * 4 + (threadIdx.x >> 6);
  const float* rp = sup + (size_t)row * Nn;
  uint* outp = pkv + (size_t)row * ELLW;
  const unsigned long long lt = (1ull << lane) - 1ull;
  int off = 0;
  for (int j0 = 0; j0 < Nn; j0 += 64) {
    float v = rp[j0 + lane];
    unsigned long long m = __ballot(v != 0.0f);
    if (v != 0.0f) {
      int pos = off + (int)__popcll(m & lt);
      if (pos < ELLW) outp[pos] = ((uint)f2h(v) << 16) | ((uint)(j0 + lane) << 4);
    }
    off += (int)__popcll(m);
  }
  if (off > ELLW) off = ELLW;
  const int c4 = (off + 3) & ~3;                 // <=112, 112%4==0
  if (lane < c4 - off) outp[off + lane] = 0u;    // val=0: contributes nothing
  if (lane == 0) rcnt[row] = c4;
}

// ---------------- ELL transpose -> column-major pT[i][8192] ----------------
// Walk e-loads become 256B coalesced wave-loads (was 64 cache lines per wave-load).
__global__ __launch_bounds__(256) void k_tr(const uint* __restrict__ pkv, uint* __restrict__ pT) {
  __shared__ uint tile[64*113];                  // stride 113: odd vs 32 banks
  const int g = blockIdx.x, t = threadIdx.x;     // 128 blocks x 64 rows
  const uint* src = pkv + (size_t)g * 64 * ELLW;
  for (int idx = t; idx < 64*ELLW; idx += 256) {
    const int r = idx / ELLW, i = idx - r*ELLW;
    tile[r*113 + i] = src[idx];
  }
  __syncthreads();
  for (int idx = t; idx < 64*ELLW; idx += 256) {
    const int i = idx >> 6, r = idx & 63;
    pT[(size_t)i*8192 + g*64 + r] = tile[r*113 + i];
  }
}

// ---------------- x0 = [inputs | hx] fp16 in [n][b][f], vectorized ----------------
__global__ __launch_bounds__(256) void k_bx0(const float* __restrict__ inp, const float* __restrict__ hx,
                                             ushort* __restrict__ x0) {
  const int n = blockIdx.x;
  const int b = threadIdx.x >> 2, q = threadIdx.x & 3;
  const float* hp = hx + (size_t)b*NU + (size_t)n*Uu + q*16;
  ushort* xp = x0 + (size_t)n*RL + b*66;
  #pragma unroll
  for (int i = 0; i < 4; ++i) {
    const float4 v = *(const float4*)&hp[i*4];
    const int o = 2 + q*16 + i*4;
    *(uint*)&xp[o]     = (uint)f2h(v.x) | ((uint)f2h(v.y) << 16);
    *(uint*)&xp[o + 2] = (uint)f2h(v.z) | ((uint)f2h(v.w) << 16);
  }
  if (q == 0) {
    const float2 iv = *(const float2*)&inp[(size_t)b*(size_t)(Nn*2) + (size_t)n*2];
    *(uint*)&xp[0] = (uint)f2h(iv.x) | ((uint)f2h(iv.y) << 16);
  }
}

// ---------------- 4 entries: 4 ds_read_b128 issued together, then 16 v_pk_fma_f16 ----------------
#define PROC4(EA, EB, EC, ED)                                                      \
  {                                                                                \
    const uint4 w0 = *(const uint4*)(slb + (EA & 0xfff0u));                        \
    const uint4 w1 = *(const uint4*)(slb + (EB & 0xfff0u));                        \
    const uint4 w2 = *(const uint4*)(slb + (EC & 0xfff0u));                        \
    const uint4 w3 = *(const uint4*)(slb + (ED & 0xfff0u));                        \
    const __half2 av0 = u2h(__builtin_amdgcn_perm(EA, EA, 0x03020302u));           \
    const __half2 av1 = u2h(__builtin_amdgcn_perm(EB, EB, 0x03020302u));           \
    const __half2 av2 = u2h(__builtin_amdgcn_perm(EC, EC, 0x03020302u));           \
    const __half2 av3 = u2h(__builtin_amdgcn_perm(ED, ED, 0x03020302u));           \
    a01 = __hfma2(av0, u2h(w0.x), a01); a23 = __hfma2(av0, u2h(w0.y), a23);        \
    a45 = __hfma2(av0, u2h(w0.z), a45); a67 = __hfma2(av0, u2h(w0.w), a67);        \
    a01 = __hfma2(av1, u2h(w1.x), a01); a23 = __hfma2(av1, u2h(w1.y), a23);        \
    a45 = __hfma2(av1, u2h(w1.z), a45); a67 = __hfma2(av1, u2h(w1.w), a67);        \
    a01 = __hfma2(av2, u2h(w2.x), a01); a23 = __hfma2(av2, u2h(w2.y), a23);        \
    a45 = __hfma2(av2, u2h(w2.z), a45); a67 = __hfma2(av2, u2h(w2.w), a67);        \
    a01 = __hfma2(av3, u2h(w3.x), a01); a23 = __hfma2(av3, u2h(w3.y), a23);        \
    a45 = __hfma2(av3, u2h(w3.z), a45); a67 = __hfma2(av3, u2h(w3.w), a67);        \
  }

// ---------------- SpMM: y = A@x (PASS2: y = 2*A@x - xsub), fp16 + columnar ELL ----------------
// R15 structure: 64 KiB slab (4096 rows x 8 fp16 cols), 2 blocks/CU, 8 waves/SIMD,
// natural row order, 1 lane/row, ds_read_b128 serves 8 cols, columnar coalesced
// e-loads (lane r reads pT[i*8192 + row r]) with next-batch prefetch.
// ONLY change vs R15: fp16 packed math (7 VALU/entry vs ~20) — R14's format.
template<bool PASS2>
__global__ __launch_bounds__(1024, 8) void k_spmm(const ushort* __restrict__ xin,
                                                  const ushort* __restrict__ xsub,
                                                  ushort* __restrict__ yout,
                                                  const int* __restrict__ rcnt,
                                                  const uint* __restrict__ pT) {
  __shared__ ushort slab[4096*8];                        // 64 KiB, 16B rows
  const char* slb = (const char*)slab;
  const int t = threadIdx.x, b = blockIdx.x;
  #pragma unroll 1
  for (int task = 0; task < 2; ++task) {
    int unit, r0, nr;
    if (task == 0) { unit = ((b & 7) << 6) + (b >> 3); r0 = 0; nr = 4096; }
    else           { unit = 512 + (b >> 5); r0 = (b & 31) * 128; nr = 128; }
    const int c0 = unit * 8;
    #pragma unroll 1
    for (int s = 0; s < 2; ++s) {
      if (PASS2 || s == 0) {                             // pass1 shares the x slab
        if (task | s) __syncthreads();                   // walkers done before restage
        const ushort* src = xin + (PASS2 ? (size_t)s * MATSZ : (size_t)0) + c0;
        #pragma unroll
        for (int it = 0; it < 4; ++it) {
          const int j = it * 1024 + t;
          *(uint4*)&slab[j * 8] = *(const uint4*)&src[(size_t)j * RL];
        }
        __syncthreads();
      }
      const int sb = s << 12;
      ushort* yo = yout + (size_t)s * MATSZ + c0;
      for (int r = r0 + t; r < r0 + nr; r += 1024) {     // 1 lane per output row
        const int rb = sb + r;
        const int c = rcnt[rb];                          // multiple of 4, >= 4
        const uint* pp = pT + rb;                        // entry i at pp[i*8192]
        __half2 a01 = u2h(0), a23 = u2h(0), a45 = u2h(0), a67 = u2h(0);
        uint e0 = pp[0], e1 = pp[8192], e2 = pp[16384], e3 = pp[24576];
        pp += 32768;
        for (int i = 4; i < c; i += 4) {                 // prefetch next 4 columns
          const uint f0 = pp[0], f1 = pp[8192], f2 = pp[16384], f3 = pp[24576];
          pp += 32768;
          PROC4(e0, e1, e2, e3);
          e0 = f0; e1 = f1; e2 = f2; e3 = f3;
        }
        PROC4(e0, e1, e2, e3);
        uint4 o;
        if (PASS2) {
          const uint4 xv = *(const uint4*)&xsub[(size_t)r*RL + c0];
          o.x = h2u(__hsub2(__hadd2(a01, a01), u2h(xv.x)));
          o.y = h2u(__hsub2(__hadd2(a23, a23), u2h(xv.y)));
          o.z = h2u(__hsub2(__hadd2(a45, a45), u2h(xv.z)));
          o.w = h2u(__hsub2(__hadd2(a67, a67), u2h(xv.w)));
        } else {
          o.x = h2u(a01); o.y = h2u(a23); o.z = h2u(a45); o.w = h2u(a67);
        }
        *(uint4*)&yo[(size_t)r*RL] = o;
      }
    }
  }
}

// ---------------- W pre-pack into MFMA B-fragment order (fp16) ----------------
__global__ __launch_bounds__(256) void k_wpack(const float* __restrict__ W1, const float* __restrict__ W2,
                                               ushort* __restrict__ Wp1, ushort* __restrict__ Wp2) {
  const int tid = blockIdx.x*256 + threadIdx.x;
  const int i = tid & 7, l = (tid >> 3) & 63;
  if (tid < 45056) {
    const int g = tid >> 9, tt = g / 11, kk = g % 11;
    const int r = kk*32 + (l>>4)*8 + i, c = tt*16 + (l & 15);
    Wp1[tid] = (r < 330) ? f2h(W1[(size_t)r*128 + c]) : (ushort)0;
  } else {
    const int t2 = tid - 45056;
    const int g = t2 >> 9, tt = g / 11, kk = g % 11;
    const int r = kk*32 + (l>>4)*8 + i, c = tt*16 + (l & 15);
    Wp2[t2] = (r < 330) ? f2h(W2[(size_t)r*64 + c]) : (ushort)0;
  }
}

// ---------------- gconv1 output GEMM (MFMA f16), fused sigmoid + r*hx + u ----------------
__global__ __launch_bounds__(256) void k_gemm1(const ushort* __restrict__ x0, const ushort* __restrict__ y1,
                                               const ushort* __restrict__ y2, const ushort* __restrict__ Wp,
                                               const float* __restrict__ bias, const float* __restrict__ hx,
                                               ushort* __restrict__ x0w, ushort* __restrict__ ubuf) {
  __shared__ ushort Xs[64*XSTR];                  // [b][k], k = f*5+m, padded to 352
  const int n = blockIdx.x, t = threadIdx.x;
  for (int q = t; q < 64*XSTR/4; q += 256) ((unsigned long long*)Xs)[q] = 0ull;
  __syncthreads();
  for (int m = 0; m < 5; ++m) {
    const ushort* mp;
    if (m == 0) mp = x0; else { mp = (m & 1) ? y1 : y2; if (m >= 3) mp += MATSZ; }
    mp += (size_t)n * RL;
    for (int q = t; q < RL; q += 256) {
      const int b = q / 66, f = q - b*66;
      Xs[b*XSTR + f*5 + m] = mp[q];
    }
  }
  __syncthreads();
  const int w = t >> 6, l = t & 63;
  const int b0 = w * 16;
  f32x4 acc[8];
  for (int i = 0; i < 8; ++i) acc[i] = (f32x4){0.f,0.f,0.f,0.f};
  const int arow = b0 + (l & 15), koff0 = (l >> 4) * 8;
  for (int kk = 0; kk < 11; ++kk) {
    const short8 af = *(const short8*)&Xs[arow*XSTR + kk*32 + koff0];
    #pragma unroll
    for (int tt = 0; tt < 8; ++tt) {
      const short8 bf = *(const short8*)&Wp[(((size_t)tt*11 + kk)*64 + l)*8];
      acc[tt] = __builtin_amdgcn_mfma_f32_16x16x32_f16(af, bf, acc[tt], 0, 0, 0);
    }
  }
  const int rg = (l >> 4) * 4;
  #pragma unroll
  for (int tt = 0; tt < 8; ++tt) {
    const int o = tt*16 + (l & 15);
    const float bs = bias[o];
    #pragma unroll
    for (int r = 0; r < 4; ++r) {
      const int b = b0 + rg + r;
      const float v = acc[tt][r] + bs;
      const float sg = 1.0f / (1.0f + __expf(-v));
      if (o < Uu) {
        const float h = hx[(size_t)b*NU + (size_t)n*Uu + o];
        x0w[(size_t)n*RL + b*66 + 2 + o] = f2h(sg * h);
      } else {
        ubuf[(size_t)b*NU + (size_t)n*Uu + (o - Uu)] = f2h(sg);
      }
    }
  }
}

// ---------------- gconv2 output GEMM (MFMA f16), fused tanh + final gate ----------------
__global__ __launch_bounds__(256) void k_gemm2(const ushort* __restrict__ x0, const ushort* __restrict__ y1,
                                               const ushort* __restrict__ y2, const ushort* __restrict__ Wp,
                                               const float* __restrict__ bias, const float* __restrict__ hx,
                                               const ushort* __restrict__ ubuf, float* __restrict__ out) {
  __shared__ ushort Xs[64*XSTR];
  const int n = blockIdx.x, t = threadIdx.x;
  for (int q = t; q < 64*XSTR/4; q += 256) ((unsigned long long*)Xs)[q] = 0ull;
  __syncthreads();
  for (int m = 0; m < 5; ++m) {
    const ushort* mp;
    if (m == 0) mp = x0; else { mp = (m & 1) ? y1 : y2; if (m >= 3) mp += MATSZ; }
    mp += (size_t)n * RL;
    for (int q = t; q < RL; q += 256) {
      const int b = q / 66, f = q - b*66;
      Xs[b*XSTR + f*5 + m] = mp[q];
    }
  }
  __syncthreads();
  const int w = t >> 6, l = t & 63;
  const int b0 = w * 16;
  f32x4 acc[4];
  for (int i = 0; i < 4; ++i) acc[i] = (f32x4){0.f,0.f,0.f,0.f};
  const int arow = b0 + (l & 15), koff0 = (l >> 4) * 8;
  for (int kk = 0; kk < 11; ++kk) {
    const short8 af = *(const short8*)&Xs[arow*XSTR + kk*32 + koff0];
    #pragma unroll
    for (int tt = 0; tt < 4; ++tt) {
      const short8 bf = *(const short8*)&Wp[(((size_t)tt*11 + kk)*64 + l)*8];
      acc[tt] = __builtin_amdgcn_mfma_f32_16x16x32_f16(af, bf, acc[tt], 0, 0, 0);
    }
  }
  const int rg = (l >> 4) * 4;
  #pragma unroll
  for (int tt = 0; tt < 4; ++tt) {
    const int o = tt*16 + (l & 15);
    const float bs = bias[o];
    #pragma unroll
    for (int r = 0; r < 4; ++r) {
      const int b = b0 + rg + r;
      const float c = tanhf(acc[tt][r] + bs);
      const size_t ix = (size_t)b*NU + (size_t)n*Uu + o;
      const float u = __half2float(__ushort_as_half(ubuf[ix]));
      const float h = hx[ix];
      out[ix] = u*h + (1.0f - u)*c;
    }
  }
}

extern "C" void kernel_launch(void* const* d_in, const int* in_sizes, int n_in,
                              void* d_out, int out_size, void* d_ws, size_t ws_size,
                              hipStream_t stream) {
  const float* inp = (const float*)d_in[0];
  const float* hx  = (const float*)d_in[1];
  const float* sup = (const float*)d_in[2];
  const float* ruW = (const float*)d_in[3];
  const float* ruB = (const float*)d_in[4];
  const float* gW  = (const float*)d_in[5];
  const float* gB  = (const float*)d_in[6];
  float* out = (float*)d_out;

  // workspace: x0 | y1[2] | y2[2] | u | Wpk | ELL(row) | ELL(col) | rcnt  (~215 MB)
  ushort* x0   = (ushort*)d_ws;
  ushort* y1   = x0 + MATSZ;
  ushort* y2   = y1 + 2*MATSZ;
  ushort* ubuf = y2 + 2*MATSZ;
  ushort* Wp1  = ubuf + (size_t)Bb*NU;
  ushort* Wp2  = Wp1 + 45056;
  uint* pkv  = (uint*)(Wp2 + 22528);
  uint* pT   = pkv + (size_t)8192*ELLW;
  int*  rcnt = (int*)(pT + (size_t)8192*ELLW);

  k_fill<<<2048, 256, 0, stream>>>(sup, pkv, rcnt);
  k_tr<<<128, 256, 0, stream>>>(pkv, pT);
  k_wpack<<<264, 256, 0, stream>>>(ruW, gW, Wp1, Wp2);
  k_bx0<<<Nn, 256, 0, stream>>>(inp, hx, x0);

  // gconv1
  k_spmm<false><<<512, 1024, 0, stream>>>(x0, nullptr, y1, rcnt, pT);
  k_spmm<true ><<<512, 1024, 0, stream>>>(y1, x0,      y2, rcnt, pT);
  k_gemm1<<<Nn, 256, 0, stream>>>(x0, y1, y2, Wp1, ruB, hx, x0, ubuf);
  // gconv2 (x0 state slots now hold fp16(r*hx))
  k_spmm<false><<<512, 1024, 0, stream>>>(x0, nullptr, y1, rcnt, pT);
  k_spmm<true ><<<512, 1024, 0, stream>>>(y1, x0,      y2, rcnt, pT);
  k_gemm2<<<Nn, 256, 0, stream>>>(x0, y1, y2, Wp2, gB, hx, ubuf, out);
}

// Round 17
// 808.203 us; speedup vs baseline: 1.6506x; 1.0060x over previous
//
#include <hip/hip_runtime.h>
#include <hip/hip_fp16.h>
#include <math.h>
#include <stdint.h>

#define Bb 64
#define Nn 4096
#define Uu 64
#define RL 4224                         // 64*66
#define NU (Nn*Uu)
#define MATSZ ((size_t)Nn*(size_t)RL)   // elements per feature matrix
#define ELLW 112                        // ELL row capacity (avg nnz ~42), multiple of 4
#define SSTR 104                        // gemm slab k-stride: 96 (3 K-tiles) + 8 bank pad

typedef __attribute__((ext_vector_type(8))) short short8;
typedef __attribute__((ext_vector_type(4))) float f32x4;
typedef unsigned int uint;
typedef unsigned short ushort;

__device__ inline ushort f2h(float f){ return __half_as_ushort(__float2half(f)); }
__device__ inline __half2 u2h(uint u){ union{uint v;__half2 h;} c; c.v=u; return c.h; }
__device__ inline uint h2u(__half2 h){ union{__half2 h;uint v;} c; c.h=h; return c.v; }

// ---------------- ELL extraction: entry = (fp16(val)<<16) | (col<<4), pad to 4 ----------------
__global__ __launch_bounds__(256) void k_fill(const float* __restrict__ sup,
                                              uint* __restrict__ pkv, int* __restrict__ rcnt) {
  const int lane = threadIdx.x & 63;
  const int row = blockIdx.x * 4 + (threadIdx.x >> 6);
  const float* rp = sup + (size_t)row * Nn;
  uint* outp = pkv + (size_t)row * ELLW;
  const unsigned long long lt = (1ull << lane) - 1ull;
  int off = 0;
  for (int j0 = 0; j0 < Nn; j0 += 64) {
    float v = rp[j0 + lane];
    unsigned long long m = __ballot(v != 0.0f);
    if (v != 0.0f) {
      int pos = off + (int)__popcll(m & lt);
      if (pos < ELLW) outp[pos] = ((uint)f2h(v) << 16) | ((uint)(j0 + lane) << 4);
    }
    off += (int)__popcll(m);
  }
  if (off > ELLW) off = ELLW;
  const int c4 = (off + 3) & ~3;
  if (lane < c4 - off) outp[off + lane] = 0u;    // val=0: contributes nothing
  if (lane == 0) rcnt[row] = c4;
}

// ---------------- ELL transpose -> column-major pT[i][8192] ----------------
__global__ __launch_bounds__(256) void k_tr(const uint* __restrict__ pkv, uint* __restrict__ pT) {
  __shared__ uint tile[64*113];
  const int g = blockIdx.x, t = threadIdx.x;     // 128 blocks x 64 rows
  const uint* src = pkv + (size_t)g * 64 * ELLW;
  for (int idx = t; idx < 64*ELLW; idx += 256) {
    const int r = idx / ELLW, i = idx - r*ELLW;
    tile[r*113 + i] = src[idx];
  }
  __syncthreads();
  for (int idx = t; idx < 64*ELLW; idx += 256) {
    const int i = idx >> 6, r = idx & 63;
    pT[(size_t)i*8192 + g*64 + r] = tile[r*113 + i];
  }
}

// ---------------- x0 = [inputs | hx] fp16 in [n][b][f], vectorized ----------------
__global__ __launch_bounds__(256) void k_bx0(const float* __restrict__ inp, const float* __restrict__ hx,
                                             ushort* __restrict__ x0) {
  const int n = blockIdx.x;
  const int b = threadIdx.x >> 2, q = threadIdx.x & 3;
  const float* hp = hx + (size_t)b*NU + (size_t)n*Uu + q*16;
  ushort* xp = x0 + (size_t)n*RL + b*66;
  #pragma unroll
  for (int i = 0; i < 4; ++i) {
    const float4 v = *(const float4*)&hp[i*4];
    const int o = 2 + q*16 + i*4;
    *(uint*)&xp[o]     = (uint)f2h(v.x) | ((uint)f2h(v.y) << 16);
    *(uint*)&xp[o + 2] = (uint)f2h(v.z) | ((uint)f2h(v.w) << 16);
  }
  if (q == 0) {
    const float2 iv = *(const float2*)&inp[(size_t)b*(size_t)(Nn*2) + (size_t)n*2];
    *(uint*)&xp[0] = (uint)f2h(iv.x) | ((uint)f2h(iv.y) << 16);
  }
}

// ---------------- 4 entries: 4 ds_read_b128 issued together, then 16 v_pk_fma_f16 ----------------
#define PROC4(EA, EB, EC, ED)                                                      \
  {                                                                                \
    const uint4 w0 = *(const uint4*)(slb + (EA & 0xfff0u));                        \
    const uint4 w1 = *(const uint4*)(slb + (EB & 0xfff0u));                        \
    const uint4 w2 = *(const uint4*)(slb + (EC & 0xfff0u));                        \
    const uint4 w3 = *(const uint4*)(slb + (ED & 0xfff0u));                        \
    const __half2 av0 = u2h(__builtin_amdgcn_perm(EA, EA, 0x03020302u));           \
    const __half2 av1 = u2h(__builtin_amdgcn_perm(EB, EB, 0x03020302u));           \
    const __half2 av2 = u2h(__builtin_amdgcn_perm(EC, EC, 0x03020302u));           \
    const __half2 av3 = u2h(__builtin_amdgcn_perm(ED, ED, 0x03020302u));           \
    a01 = __hfma2(av0, u2h(w0.x), a01); a23 = __hfma2(av0, u2h(w0.y), a23);        \
    a45 = __hfma2(av0, u2h(w0.z), a45); a67 = __hfma2(av0, u2h(w0.w), a67);        \
    a01 = __hfma2(av1, u2h(w1.x), a01); a23 = __hfma2(av1, u2h(w1.y), a23);        \
    a45 = __hfma2(av1, u2h(w1.z), a45); a67 = __hfma2(av1, u2h(w1.w), a67);        \
    a01 = __hfma2(av2, u2h(w2.x), a01); a23 = __hfma2(av2, u2h(w2.y), a23);        \
    a45 = __hfma2(av2, u2h(w2.z), a45); a67 = __hfma2(av2, u2h(w2.w), a67);        \
    a01 = __hfma2(av3, u2h(w3.x), a01); a23 = __hfma2(av3, u2h(w3.y), a23);        \
    a45 = __hfma2(av3, u2h(w3.z), a45); a67 = __hfma2(av3, u2h(w3.w), a67);        \
  }

// ---------------- SpMM (R16, unchanged): fp16 + columnar coalesced ELL ----------------
template<bool PASS2>
__global__ __launch_bounds__(1024, 8) void k_spmm(const ushort* __restrict__ xin,
                                                  const ushort* __restrict__ xsub,
                                                  ushort* __restrict__ yout,
                                                  const int* __restrict__ rcnt,
                                                  const uint* __restrict__ pT) {
  __shared__ ushort slab[4096*8];                        // 64 KiB, 16B rows
  const char* slb = (const char*)slab;
  const int t = threadIdx.x, b = blockIdx.x;
  #pragma unroll 1
  for (int task = 0; task < 2; ++task) {
    int unit, r0, nr;
    if (task == 0) { unit = ((b & 7) << 6) + (b >> 3); r0 = 0; nr = 4096; }
    else           { unit = 512 + (b >> 5); r0 = (b & 31) * 128; nr = 128; }
    const int c0 = unit * 8;
    #pragma unroll 1
    for (int s = 0; s < 2; ++s) {
      if (PASS2 || s == 0) {
        if (task | s) __syncthreads();
        const ushort* src = xin + (PASS2 ? (size_t)s * MATSZ : (size_t)0) + c0;
        #pragma unroll
        for (int it = 0; it < 4; ++it) {
          const int j = it * 1024 + t;
          *(uint4*)&slab[j * 8] = *(const uint4*)&src[(size_t)j * RL];
        }
        __syncthreads();
      }
      const int sb = s << 12;
      ushort* yo = yout + (size_t)s * MATSZ + c0;
      for (int r = r0 + t; r < r0 + nr; r += 1024) {
        const int rb = sb + r;
        const int c = rcnt[rb];
        const uint* pp = pT + rb;
        __half2 a01 = u2h(0), a23 = u2h(0), a45 = u2h(0), a67 = u2h(0);
        uint e0 = pp[0], e1 = pp[8192], e2 = pp[16384], e3 = pp[24576];
        pp += 32768;
        for (int i = 4; i < c; i += 4) {
          const uint f0 = pp[0], f1 = pp[8192], f2 = pp[16384], f3 = pp[24576];
          pp += 32768;
          PROC4(e0, e1, e2, e3);
          e0 = f0; e1 = f1; e2 = f2; e3 = f3;
        }
        PROC4(e0, e1, e2, e3);
        uint4 o;
        if (PASS2) {
          const uint4 xv = *(const uint4*)&xsub[(size_t)r*RL + c0];
          o.x = h2u(__hsub2(__hadd2(a01, a01), u2h(xv.x)));
          o.y = h2u(__hsub2(__hadd2(a23, a23), u2h(xv.y)));
          o.z = h2u(__hsub2(__hadd2(a45, a45), u2h(xv.z)));
          o.w = h2u(__hsub2(__hadd2(a67, a67), u2h(xv.w)));
        } else {
          o.x = h2u(a01); o.y = h2u(a23); o.z = h2u(a45); o.w = h2u(a67);
        }
        *(uint4*)&yo[(size_t)r*RL] = o;
      }
    }
  }
}

// ---------------- W pre-pack, slab order: T = m*3+kt, k_in_slab f = kt*32+koffu+i ----------------
__global__ __launch_bounds__(256) void k_wpack(const float* __restrict__ W1, const float* __restrict__ W2,
                                               ushort* __restrict__ Wp1, ushort* __restrict__ Wp2) {
  const int tid = blockIdx.x*256 + threadIdx.x;      // grid 360 -> 92160
  const int i = tid & 7, l = (tid >> 3) & 63;
  const int koffu = (l >> 4) * 8;
  if (tid < 61440) {
    const int g = tid >> 9, tt = g / 15, T = g % 15;
    const int m = T / 3, kt = T % 3;
    const int f = kt*32 + koffu + i;
    const int c = tt*16 + (l & 15);
    Wp1[tid] = (f < 66) ? f2h(W1[(size_t)(f*5 + m)*128 + c]) : (ushort)0;
  } else {
    const int t2 = tid - 61440;
    const int g = t2 >> 9, tt = g / 15, T = g % 15;
    const int m = T / 3, kt = T % 3;
    const int f = kt*32 + koffu + i;
    const int c = tt*16 + (l & 15);
    Wp2[t2] = (f < 66) ? f2h(W2[(size_t)(f*5 + m)*64 + c]) : (ushort)0;
  }
}

// ---------------- slab-pipelined gemm staging helpers ----------------
// slab source: contiguous 4224 ushorts = 2112 uints; scatter to Xs[b*104+f] (f even -> 4B aligned)
#define STAGE_W(DST, J, V) { const int q_=2*(J), b_=q_/66, f_=q_-66*b_; *(uint*)&(DST)[b_*SSTR+f_] = (V); }

// ---------------- gconv1 output GEMM (slab-pipelined, MFMA f16), sigmoid + r*hx + u ----------------
__global__ __launch_bounds__(256, 6) void k_gemm1(const ushort* __restrict__ x0, const ushort* __restrict__ y1,
                                                  const ushort* __restrict__ y2, const ushort* __restrict__ Wp,
                                                  const float* __restrict__ bias, const float* __restrict__ hx,
                                                  ushort* __restrict__ x0w, ushort* __restrict__ ubuf) {
  __shared__ ushort Xs[2][64*SSTR];                // 26.6 KiB -> 6 blocks/CU
  const int n = blockIdx.x, t = threadIdx.x;
  for (int q = t; q < 2*64*SSTR/4; q += 256) ((unsigned long long*)Xs)[q] = 0ull;  // pads stay 0
  __syncthreads();
  const ushort* mats[5] = { x0 + (size_t)n*RL, y1 + (size_t)n*RL, y2 + (size_t)n*RL,
                            y1 + MATSZ + (size_t)n*RL, y2 + MATSZ + (size_t)n*RL };
  {
    const ushort* mp = mats[0];
    for (int j = t; j < 2112; j += 256) { const uint v = *(const uint*)&mp[2*j]; STAGE_W(Xs[0], j, v); }
  }
  __syncthreads();
  const int w = t >> 6, l = t & 63;
  const int b0 = w * 16;
  const int arow = b0 + (l & 15), koffu = (l >> 4) * 8;
  f32x4 acc[8];
  #pragma unroll
  for (int i = 0; i < 8; ++i) acc[i] = (f32x4){0.f,0.f,0.f,0.f};
  #pragma unroll
  for (int m = 0; m < 5; ++m) {
    const int cur = m & 1;
    uint r0v=0,r1v=0,r2v=0,r3v=0,r4v=0,r5v=0,r6v=0,r7v=0,r8v=0;
    if (m < 4) {                                   // prefetch next slab (in flight during MFMA)
      const ushort* mp = mats[m+1];
      r0v = *(const uint*)&mp[2*t];          r1v = *(const uint*)&mp[2*(t+256)];
      r2v = *(const uint*)&mp[2*(t+512)];    r3v = *(const uint*)&mp[2*(t+768)];
      r4v = *(const uint*)&mp[2*(t+1024)];   r5v = *(const uint*)&mp[2*(t+1280)];
      r6v = *(const uint*)&mp[2*(t+1536)];   r7v = *(const uint*)&mp[2*(t+1792)];
      if (t < 64) r8v = *(const uint*)&mp[2*(t+2048)];
    }
    #pragma unroll
    for (int kt = 0; kt < 3; ++kt) {
      const short8 af = *(const short8*)&Xs[cur][arow*SSTR + kt*32 + koffu];
      const int T = m*3 + kt;
      #pragma unroll
      for (int tt = 0; tt < 8; ++tt) {
        const short8 bf = *(const short8*)&Wp[(((size_t)tt*15 + T)*64 + l)*8];
        acc[tt] = __builtin_amdgcn_mfma_f32_16x16x32_f16(af, bf, acc[tt], 0, 0, 0);
      }
    }
    if (m < 4) {
      ushort* nb = Xs[cur ^ 1];
      STAGE_W(nb, t,      r0v); STAGE_W(nb, t+256,  r1v);
      STAGE_W(nb, t+512,  r2v); STAGE_W(nb, t+768,  r3v);
      STAGE_W(nb, t+1024, r4v); STAGE_W(nb, t+1280, r5v);
      STAGE_W(nb, t+1536, r6v); STAGE_W(nb, t+1792, r7v);
      if (t < 64) STAGE_W(nb, t+2048, r8v);
    }
    __syncthreads();
  }
  const int rg = (l >> 4) * 4;
  #pragma unroll
  for (int tt = 0; tt < 8; ++tt) {
    const int o = tt*16 + (l & 15);
    const float bs = bias[o];
    #pragma unroll
    for (int r = 0; r < 4; ++r) {
      const int b = b0 + rg + r;
      const float v = acc[tt][r] + bs;
      const float sg = 1.0f / (1.0f + __expf(-v));
      if (o < Uu) {
        const float h = hx[(size_t)b*NU + (size_t)n*Uu + o];
        x0w[(size_t)n*RL + b*66 + 2 + o] = f2h(sg * h);
      } else {
        ubuf[(size_t)b*NU + (size_t)n*Uu + (o - Uu)] = f2h(sg);
      }
    }
  }
}

// ---------------- gconv2 output GEMM (slab-pipelined, MFMA f16), tanh + final gate ----------------
__global__ __launch_bounds__(256, 6) void k_gemm2(const ushort* __restrict__ x0, const ushort* __restrict__ y1,
                                                  const ushort* __restrict__ y2, const ushort* __restrict__ Wp,
                                                  const float* __restrict__ bias, const float* __restrict__ hx,
                                                  const ushort* __restrict__ ubuf, float* __restrict__ out) {
  __shared__ ushort Xs[2][64*SSTR];
  const int n = blockIdx.x, t = threadIdx.x;
  for (int q = t; q < 2*64*SSTR/4; q += 256) ((unsigned long long*)Xs)[q] = 0ull;
  __syncthreads();
  const ushort* mats[5] = { x0 + (size_t)n*RL, y1 + (size_t)n*RL, y2 + (size_t)n*RL,
                            y1 + MATSZ + (size_t)n*RL, y2 + MATSZ + (size_t)n*RL };
  {
    const ushort* mp = mats[0];
    for (int j = t; j < 2112; j += 256) { const uint v = *(const uint*)&mp[2*j]; STAGE_W(Xs[0], j, v); }
  }
  __syncthreads();
  const int w = t >> 6, l = t & 63;
  const int b0 = w * 16;
  const int arow = b0 + (l & 15), koffu = (l >> 4) * 8;
  f32x4 acc[4];
  #pragma unroll
  for (int i = 0; i < 4; ++i) acc[i] = (f32x4){0.f,0.f,0.f,0.f};
  #pragma unroll
  for (int m = 0; m < 5; ++m) {
    const int cur = m & 1;
    uint r0v=0,r1v=0,r2v=0,r3v=0,r4v=0,r5v=0,r6v=0,r7v=0,r8v=0;
    if (m < 4) {
      const ushort* mp = mats[m+1];
      r0v = *(const uint*)&mp[2*t];          r1v = *(const uint*)&mp[2*(t+256)];
      r2v = *(const uint*)&mp[2*(t+512)];    r3v = *(const uint*)&mp[2*(t+768)];
      r4v = *(const uint*)&mp[2*(t+1024)];   r5v = *(const uint*)&mp[2*(t+1280)];
      r6v = *(const uint*)&mp[2*(t+1536)];   r7v = *(const uint*)&mp[2*(t+1792)];
      if (t < 64) r8v = *(const uint*)&mp[2*(t+2048)];
    }
    #pragma unroll
    for (int kt = 0; kt < 3; ++kt) {
      const short8 af = *(const short8*)&Xs[cur][arow*SSTR + kt*32 + koffu];
      const int T = m*3 + kt;
      #pragma unroll
      for (int tt = 0; tt < 4; ++tt) {
        const short8 bf = *(const short8*)&Wp[(((size_t)tt*15 + T)*64 + l)*8];
        acc[tt] = __builtin_amdgcn_mfma_f32_16x16x32_f16(af, bf, acc[tt], 0, 0, 0);
      }
    }
    if (m < 4) {
      ushort* nb = Xs[cur ^ 1];
      STAGE_W(nb, t,      r0v); STAGE_W(nb, t+256,  r1v);
      STAGE_W(nb, t+512,  r2v); STAGE_W(nb, t+768,  r3v);
      STAGE_W(nb, t+1024, r4v); STAGE_W(nb, t+1280, r5v);
      STAGE_W(nb, t+1536, r6v); STAGE_W(nb, t+1792, r7v);
      if (t < 64) STAGE_W(nb, t+2048, r8v);
    }
    __syncthreads();
  }
  const int rg = (l >> 4) * 4;
  #pragma unroll
  for (int tt = 0; tt < 4; ++tt) {
    const int o = tt*16 + (l & 15);
    const float bs = bias[o];
    #pragma unroll
    for (int r = 0; r < 4; ++r) {
      const int b = b0 + rg + r;
      const float c = tanhf(acc[tt][r] + bs);
      const size_t ix = (size_t)b*NU + (size_t)n*Uu + o;
      const float u = __half2float(__ushort_as_half(ubuf[ix]));
      const float h = hx[ix];
      out[ix] = u*h + (1.0f - u)*c;
    }
  }
}

extern "C" void kernel_launch(void* const* d_in, const int* in_sizes, int n_in,
                              void* d_out, int out_size, void* d_ws, size_t ws_size,
                              hipStream_t stream) {
  const float* inp = (const float*)d_in[0];
  const float* hx  = (const float*)d_in[1];
  const float* sup = (const float*)d_in[2];
  const float* ruW = (const float*)d_in[3];
  const float* ruB = (const float*)d_in[4];
  const float* gW  = (const float*)d_in[5];
  const float* gB  = (const float*)d_in[6];
  float* out = (float*)d_out;

  // workspace: x0 | y1[2] | y2[2] | u | Wpk | ELL(row) | ELL(col) | rcnt  (~214 MB)
  ushort* x0   = (ushort*)d_ws;
  ushort* y1   = x0 + MATSZ;
  ushort* y2   = y1 + 2*MATSZ;
  ushort* ubuf = y2 + 2*MATSZ;
  ushort* Wp1  = ubuf + (size_t)Bb*NU;
  ushort* Wp2  = Wp1 + 61440;
  uint* pkv  = (uint*)(Wp2 + 30720);
  uint* pT   = pkv + (size_t)8192*ELLW;
  int*  rcnt = (int*)(pT + (size_t)8192*ELLW);

  k_fill<<<2048, 256, 0, stream>>>(sup, pkv, rcnt);
  k_tr<<<128, 256, 0, stream>>>(pkv, pT);
  k_wpack<<<360, 256, 0, stream>>>(ruW, gW, Wp1, Wp2);
  k_bx0<<<Nn, 256, 0, stream>>>(inp, hx, x0);

  // gconv1
  k_spmm<false><<<512, 1024, 0, stream>>>(x0, nullptr, y1, rcnt, pT);
  k_spmm<true ><<<512, 1024, 0, stream>>>(y1, x0,      y2, rcnt, pT);
  k_gemm1<<<Nn, 256, 0, stream>>>(x0, y1, y2, Wp1, ruB, hx, x0, ubuf);
  // gconv2 (x0 state slots now hold fp16(r*hx))
  k_spmm<false><<<512, 1024, 0, stream>>>(x0, nullptr, y1, rcnt, pT);
  k_spmm<true ><<<512, 1024, 0, stream>>>(y1, x0,      y2, rcnt, pT);
  k_gemm2<<<Nn, 256, 0, stream>>>(x0, y1, y2, Wp2, gB, hx, ubuf, out);
}

// Round 18
// 759.727 us; speedup vs baseline: 1.7559x; 1.0638x over previous
//
#include <hip/hip_runtime.h>
#include <hip/hip_fp16.h>
#include <math.h>
#include <stdint.h>

#define Bb 64
#define Nn 4096
#define Uu 64
#define RL 4224                         // 64*66
#define NU (Nn*Uu)
#define MATSZ ((size_t)Nn*(size_t)RL)   // elements per feature matrix
#define ELLW 112                        // ELL row capacity (avg nnz ~42), multiple of 4
#define SSTR 104                        // gemm slab k-stride: 96 (3 K-tiles) + 8 bank pad

typedef __attribute__((ext_vector_type(8))) short short8;
typedef __attribute__((ext_vector_type(4))) float f32x4;
typedef unsigned int uint;
typedef unsigned short ushort;

__device__ inline ushort f2h(float f){ return __half_as_ushort(__float2half(f)); }
__device__ inline __half2 u2h(uint u){ union{uint v;__half2 h;} c; c.v=u; return c.h; }
__device__ inline uint h2u(__half2 h){ union{__half2 h;uint v;} c; c.h=h; return c.v; }
__device__ inline float h2f_lo(uint u){ return __half2float(__ushort_as_half((ushort)(u & 0xffffu))); }
__device__ inline float h2f_hi(uint u){ return __half2float(__ushort_as_half((ushort)(u >> 16))); }

// ---------------- ELL extraction: entry = (fp16(val)<<16) | (col<<4), pad to 4 ----------------
__global__ __launch_bounds__(256) void k_fill(const float* __restrict__ sup,
                                              uint* __restrict__ pkv, int* __restrict__ rcnt) {
  const int lane = threadIdx.x & 63;
  const int row = blockIdx.x * 4 + (threadIdx.x >> 6);
  const float* rp = sup + (size_t)row * Nn;
  uint* outp = pkv + (size_t)row * ELLW;
  const unsigned long long lt = (1ull << lane) - 1ull;
  int off = 0;
  for (int j0 = 0; j0 < Nn; j0 += 64) {
    float v = rp[j0 + lane];
    unsigned long long m = __ballot(v != 0.0f);
    if (v != 0.0f) {
      int pos = off + (int)__popcll(m & lt);
      if (pos < ELLW) outp[pos] = ((uint)f2h(v) << 16) | ((uint)(j0 + lane) << 4);
    }
    off += (int)__popcll(m);
  }
  if (off > ELLW) off = ELLW;
  const int c4 = (off + 3) & ~3;
  if (lane < c4 - off) outp[off + lane] = 0u;    // val=0: contributes nothing
  if (lane == 0) rcnt[row] = c4;
}

// ---------------- ELL transpose -> column-major pT[i][8192] ----------------
__global__ __launch_bounds__(256) void k_tr(const uint* __restrict__ pkv, uint* __restrict__ pT) {
  __shared__ uint tile[64*113];
  const int g = blockIdx.x, t = threadIdx.x;     // 128 blocks x 64 rows
  const uint* src = pkv + (size_t)g * 64 * ELLW;
  for (int idx = t; idx < 64*ELLW; idx += 256) {
    const int r = idx / ELLW, i = idx - r*ELLW;
    tile[r*113 + i] = src[idx];
  }
  __syncthreads();
  for (int idx = t; idx < 64*ELLW; idx += 256) {
    const int i = idx >> 6, r = idx & 63;
    pT[(size_t)i*8192 + g*64 + r] = tile[r*113 + i];
  }
}

// ---------------- x0 = [inputs | hx] fp16 in [n][b][f], vectorized ----------------
__global__ __launch_bounds__(256) void k_bx0(const float* __restrict__ inp, const float* __restrict__ hx,
                                             ushort* __restrict__ x0) {
  const int n = blockIdx.x;
  const int b = threadIdx.x >> 2, q = threadIdx.x & 3;
  const float* hp = hx + (size_t)b*NU + (size_t)n*Uu + q*16;
  ushort* xp = x0 + (size_t)n*RL + b*66;
  #pragma unroll
  for (int i = 0; i < 4; ++i) {
    const float4 v = *(const float4*)&hp[i*4];
    const int o = 2 + q*16 + i*4;
    *(uint*)&xp[o]     = (uint)f2h(v.x) | ((uint)f2h(v.y) << 16);
    *(uint*)&xp[o + 2] = (uint)f2h(v.z) | ((uint)f2h(v.w) << 16);
  }
  if (q == 0) {
    const float2 iv = *(const float2*)&inp[(size_t)b*(size_t)(Nn*2) + (size_t)n*2];
    *(uint*)&xp[0] = (uint)f2h(iv.x) | ((uint)f2h(iv.y) << 16);
  }
}

// ---------------- 4 entries: 4 ds_read_b128 issued together, then 16 v_pk_fma_f16 ----------------
#define PROC4(EA, EB, EC, ED)                                                      \
  {                                                                                \
    const uint4 w0 = *(const uint4*)(slb + (EA & 0xfff0u));                        \
    const uint4 w1 = *(const uint4*)(slb + (EB & 0xfff0u));                        \
    const uint4 w2 = *(const uint4*)(slb + (EC & 0xfff0u));                        \
    const uint4 w3 = *(const uint4*)(slb + (ED & 0xfff0u));                        \
    const __half2 av0 = u2h(__builtin_amdgcn_perm(EA, EA, 0x03020302u));           \
    const __half2 av1 = u2h(__builtin_amdgcn_perm(EB, EB, 0x03020302u));           \
    const __half2 av2 = u2h(__builtin_amdgcn_perm(EC, EC, 0x03020302u));           \
    const __half2 av3 = u2h(__builtin_amdgcn_perm(ED, ED, 0x03020302u));           \
    a01 = __hfma2(av0, u2h(w0.x), a01); a23 = __hfma2(av0, u2h(w0.y), a23);        \
    a45 = __hfma2(av0, u2h(w0.z), a45); a67 = __hfma2(av0, u2h(w0.w), a67);        \
    a01 = __hfma2(av1, u2h(w1.x), a01); a23 = __hfma2(av1, u2h(w1.y), a23);        \
    a45 = __hfma2(av1, u2h(w1.z), a45); a67 = __hfma2(av1, u2h(w1.w), a67);        \
    a01 = __hfma2(av2, u2h(w2.x), a01); a23 = __hfma2(av2, u2h(w2.y), a23);        \
    a45 = __hfma2(av2, u2h(w2.z), a45); a67 = __hfma2(av2, u2h(w2.w), a67);        \
    a01 = __hfma2(av3, u2h(w3.x), a01); a23 = __hfma2(av3, u2h(w3.y), a23);        \
    a45 = __hfma2(av3, u2h(w3.z), a45); a67 = __hfma2(av3, u2h(w3.w), a67);        \
  }

// ---------------- SpMM (R16, unchanged): fp16 + columnar coalesced ELL ----------------
template<bool PASS2>
__global__ __launch_bounds__(1024, 8) void k_spmm(const ushort* __restrict__ xin,
                                                  const ushort* __restrict__ xsub,
                                                  ushort* __restrict__ yout,
                                                  const int* __restrict__ rcnt,
                                                  const uint* __restrict__ pT) {
  __shared__ ushort slab[4096*8];                        // 64 KiB, 16B rows
  const char* slb = (const char*)slab;
  const int t = threadIdx.x, b = blockIdx.x;
  #pragma unroll 1
  for (int task = 0; task < 2; ++task) {
    int unit, r0, nr;
    if (task == 0) { unit = ((b & 7) << 6) + (b >> 3); r0 = 0; nr = 4096; }
    else           { unit = 512 + (b >> 5); r0 = (b & 31) * 128; nr = 128; }
    const int c0 = unit * 8;
    #pragma unroll 1
    for (int s = 0; s < 2; ++s) {
      if (PASS2 || s == 0) {
        if (task | s) __syncthreads();
        const ushort* src = xin + (PASS2 ? (size_t)s * MATSZ : (size_t)0) + c0;
        #pragma unroll
        for (int it = 0; it < 4; ++it) {
          const int j = it * 1024 + t;
          *(uint4*)&slab[j * 8] = *(const uint4*)&src[(size_t)j * RL];
        }
        __syncthreads();
      }
      const int sb = s << 12;
      ushort* yo = yout + (size_t)s * MATSZ + c0;
      for (int r = r0 + t; r < r0 + nr; r += 1024) {
        const int rb = sb + r;
        const int c = rcnt[rb];
        const uint* pp = pT + rb;
        __half2 a01 = u2h(0), a23 = u2h(0), a45 = u2h(0), a67 = u2h(0);
        uint e0 = pp[0], e1 = pp[8192], e2 = pp[16384], e3 = pp[24576];
        pp += 32768;
        for (int i = 4; i < c; i += 4) {
          const uint f0 = pp[0], f1 = pp[8192], f2 = pp[16384], f3 = pp[24576];
          pp += 32768;
          PROC4(e0, e1, e2, e3);
          e0 = f0; e1 = f1; e2 = f2; e3 = f3;
        }
        PROC4(e0, e1, e2, e3);
        uint4 o;
        if (PASS2) {
          const uint4 xv = *(const uint4*)&xsub[(size_t)r*RL + c0];
          o.x = h2u(__hsub2(__hadd2(a01, a01), u2h(xv.x)));
          o.y = h2u(__hsub2(__hadd2(a23, a23), u2h(xv.y)));
          o.z = h2u(__hsub2(__hadd2(a45, a45), u2h(xv.z)));
          o.w = h2u(__hsub2(__hadd2(a67, a67), u2h(xv.w)));
        } else {
          o.x = h2u(a01); o.y = h2u(a23); o.z = h2u(a45); o.w = h2u(a67);
        }
        *(uint4*)&yo[(size_t)r*RL] = o;
      }
    }
  }
}

// ---------------- W pre-pack, slab order: T = m*3+kt, k_in_slab f = kt*32+koffu+i ----------------
__global__ __launch_bounds__(256) void k_wpack(const float* __restrict__ W1, const float* __restrict__ W2,
                                               ushort* __restrict__ Wp1, ushort* __restrict__ Wp2) {
  const int tid = blockIdx.x*256 + threadIdx.x;      // grid 360 -> 92160
  const int i = tid & 7, l = (tid >> 3) & 63;
  const int koffu = (l >> 4) * 8;
  if (tid < 61440) {
    const int g = tid >> 9, tt = g / 15, T = g % 15;
    const int m = T / 3, kt = T % 3;
    const int f = kt*32 + koffu + i;
    const int c = tt*16 + (l & 15);
    Wp1[tid] = (f < 66) ? f2h(W1[(size_t)(f*5 + m)*128 + c]) : (ushort)0;
  } else {
    const int t2 = tid - 61440;
    const int g = t2 >> 9, tt = g / 15, T = g % 15;
    const int m = T / 3, kt = T % 3;
    const int f = kt*32 + koffu + i;
    const int c = tt*16 + (l & 15);
    Wp2[t2] = (f < 66) ? f2h(W2[(size_t)(f*5 + m)*64 + c]) : (ushort)0;
  }
}

// slab source: contiguous 4224 ushorts = 2112 uints; scatter to Xs[b*104+f] (f even -> 4B aligned)
#define STAGE_W(DST, J, V) { const int q_=2*(J), b_=q_/66, f_=q_-66*b_; *(uint*)&(DST)[b_*SSTR+f_] = (V); }

// ---------------- gconv1 output GEMM (slab-pipelined, MFMA f16), sigmoid + r*hx + u ----------------
// Epilogue via LDS: phase1 writes activation to Os[b][o] (fp16, stride 132); phase2
// re-reads contiguously and emits fully-coalesced vector stores (no scattered 2B stores).
__global__ __launch_bounds__(256, 6) void k_gemm1(const ushort* __restrict__ x0, const ushort* __restrict__ y1,
                                                  const ushort* __restrict__ y2, const ushort* __restrict__ Wp,
                                                  const float* __restrict__ bias, const float* __restrict__ hx,
                                                  ushort* __restrict__ x0w, ushort* __restrict__ ubuf) {
  __shared__ ushort Xs[2][64*SSTR];                // 26.6 KiB -> 6 blocks/CU
  const int n = blockIdx.x, t = threadIdx.x;
  for (int q = t; q < 2*64*SSTR/4; q += 256) ((unsigned long long*)Xs)[q] = 0ull;  // pads stay 0
  __syncthreads();
  const ushort* mats[5] = { x0 + (size_t)n*RL, y1 + (size_t)n*RL, y2 + (size_t)n*RL,
                            y1 + MATSZ + (size_t)n*RL, y2 + MATSZ + (size_t)n*RL };
  {
    const ushort* mp = mats[0];
    for (int j = t; j < 2112; j += 256) { const uint v = *(const uint*)&mp[2*j]; STAGE_W(Xs[0], j, v); }
  }
  __syncthreads();
  const int w = t >> 6, l = t & 63;
  const int b0 = w * 16;
  const int arow = b0 + (l & 15), koffu = (l >> 4) * 8;
  f32x4 acc[8];
  #pragma unroll
  for (int i = 0; i < 8; ++i) acc[i] = (f32x4){0.f,0.f,0.f,0.f};
  #pragma unroll
  for (int m = 0; m < 5; ++m) {
    const int cur = m & 1;
    uint r0v=0,r1v=0,r2v=0,r3v=0,r4v=0,r5v=0,r6v=0,r7v=0,r8v=0;
    if (m < 4) {                                   // prefetch next slab
      const ushort* mp = mats[m+1];
      r0v = *(const uint*)&mp[2*t];          r1v = *(const uint*)&mp[2*(t+256)];
      r2v = *(const uint*)&mp[2*(t+512)];    r3v = *(const uint*)&mp[2*(t+768)];
      r4v = *(const uint*)&mp[2*(t+1024)];   r5v = *(const uint*)&mp[2*(t+1280)];
      r6v = *(const uint*)&mp[2*(t+1536)];   r7v = *(const uint*)&mp[2*(t+1792)];
      if (t < 64) r8v = *(const uint*)&mp[2*(t+2048)];
    }
    #pragma unroll
    for (int kt = 0; kt < 3; ++kt) {
      const short8 af = *(const short8*)&Xs[cur][arow*SSTR + kt*32 + koffu];
      const int T = m*3 + kt;
      #pragma unroll
      for (int tt = 0; tt < 8; ++tt) {
        const short8 bf = *(const short8*)&Wp[(((size_t)tt*15 + T)*64 + l)*8];
        acc[tt] = __builtin_amdgcn_mfma_f32_16x16x32_f16(af, bf, acc[tt], 0, 0, 0);
      }
    }
    if (m < 4) {
      ushort* nb = Xs[cur ^ 1];
      STAGE_W(nb, t,      r0v); STAGE_W(nb, t+256,  r1v);
      STAGE_W(nb, t+512,  r2v); STAGE_W(nb, t+768,  r3v);
      STAGE_W(nb, t+1024, r4v); STAGE_W(nb, t+1280, r5v);
      STAGE_W(nb, t+1536, r6v); STAGE_W(nb, t+1792, r7v);
      if (t < 64) STAGE_W(nb, t+2048, r8v);
    }
    __syncthreads();
  }
  // phase 1: activation -> LDS Os[b][o], fp16, stride 132 (reuses Xs; 16.9 KB < 26.6 KB)
  ushort* Os = (ushort*)Xs;
  const int rg = (l >> 4) * 4;
  #pragma unroll
  for (int tt = 0; tt < 8; ++tt) {
    const int o = tt*16 + (l & 15);
    const float bs = bias[o];
    #pragma unroll
    for (int r = 0; r < 4; ++r) {
      const int b = b0 + rg + r;
      const float v = acc[tt][r] + bs;
      Os[b*132 + o] = f2h(1.0f / (1.0f + __expf(-v)));
    }
  }
  __syncthreads();
  // phase 2: coalesced outputs. thread t -> (b = t>>2, 16-wide o segment q = t&3)
  {
    const int b = t >> 2, q = t & 3;
    const float* hp = hx + (size_t)b*NU + (size_t)n*Uu + q*16;
    ushort* xw = x0w + (size_t)n*RL + b*66 + 2 + q*16;
    const ushort* os = &Os[b*132 + q*16];
    #pragma unroll
    for (int i = 0; i < 4; ++i) {                  // r gate: x0w = sg * hx
      const float4 h4 = *(const float4*)&hp[i*4];
      const float s0 = __half2float(__ushort_as_half(os[i*4+0]));
      const float s1 = __half2float(__ushort_as_half(os[i*4+1]));
      const float s2 = __half2float(__ushort_as_half(os[i*4+2]));
      const float s3 = __half2float(__ushort_as_half(os[i*4+3]));
      *(uint*)&xw[i*4]     = (uint)f2h(s0*h4.x) | ((uint)f2h(s1*h4.y) << 16);
      *(uint*)&xw[i*4 + 2] = (uint)f2h(s2*h4.z) | ((uint)f2h(s3*h4.w) << 16);
    }
    ushort* uw = ubuf + (size_t)b*NU + (size_t)n*Uu + q*16;
    const ushort* os2 = &Os[b*132 + 64 + q*16];
    #pragma unroll
    for (int i = 0; i < 8; ++i) {                  // u gate: copy fp16 pairs
      *(uint*)&uw[i*2] = (uint)os2[i*2] | ((uint)os2[i*2+1] << 16);
    }
  }
}

// ---------------- gconv2 output GEMM (slab-pipelined, MFMA f16), tanh + final gate ----------------
__global__ __launch_bounds__(256, 6) void k_gemm2(const ushort* __restrict__ x0, const ushort* __restrict__ y1,
                                                  const ushort* __restrict__ y2, const ushort* __restrict__ Wp,
                                                  const float* __restrict__ bias, const float* __restrict__ hx,
                                                  const ushort* __restrict__ ubuf, float* __restrict__ out) {
  __shared__ ushort Xs[2][64*SSTR];
  const int n = blockIdx.x, t = threadIdx.x;
  for (int q = t; q < 2*64*SSTR/4; q += 256) ((unsigned long long*)Xs)[q] = 0ull;
  __syncthreads();
  const ushort* mats[5] = { x0 + (size_t)n*RL, y1 + (size_t)n*RL, y2 + (size_t)n*RL,
                            y1 + MATSZ + (size_t)n*RL, y2 + MATSZ + (size_t)n*RL };
  {
    const ushort* mp = mats[0];
    for (int j = t; j < 2112; j += 256) { const uint v = *(const uint*)&mp[2*j]; STAGE_W(Xs[0], j, v); }
  }
  __syncthreads();
  const int w = t >> 6, l = t & 63;
  const int b0 = w * 16;
  const int arow = b0 + (l & 15), koffu = (l >> 4) * 8;
  f32x4 acc[4];
  #pragma unroll
  for (int i = 0; i < 4; ++i) acc[i] = (f32x4){0.f,0.f,0.f,0.f};
  #pragma unroll
  for (int m = 0; m < 5; ++m) {
    const int cur = m & 1;
    uint r0v=0,r1v=0,r2v=0,r3v=0,r4v=0,r5v=0,r6v=0,r7v=0,r8v=0;
    if (m < 4) {
      const ushort* mp = mats[m+1];
      r0v = *(const uint*)&mp[2*t];          r1v = *(const uint*)&mp[2*(t+256)];
      r2v = *(const uint*)&mp[2*(t+512)];    r3v = *(const uint*)&mp[2*(t+768)];
      r4v = *(const uint*)&mp[2*(t+1024)];   r5v = *(const uint*)&mp[2*(t+1280)];
      r6v = *(const uint*)&mp[2*(t+1536)];   r7v = *(const uint*)&mp[2*(t+1792)];
      if (t < 64) r8v = *(const uint*)&mp[2*(t+2048)];
    }
    #pragma unroll
    for (int kt = 0; kt < 3; ++kt) {
      const short8 af = *(const short8*)&Xs[cur][arow*SSTR + kt*32 + koffu];
      const int T = m*3 + kt;
      #pragma unroll
      for (int tt = 0; tt < 4; ++tt) {
        const short8 bf = *(const short8*)&Wp[(((size_t)tt*15 + T)*64 + l)*8];
        acc[tt] = __builtin_amdgcn_mfma_f32_16x16x32_f16(af, bf, acc[tt], 0, 0, 0);
      }
    }
    if (m < 4) {
      ushort* nb = Xs[cur ^ 1];
      STAGE_W(nb, t,      r0v); STAGE_W(nb, t+256,  r1v);
      STAGE_W(nb, t+512,  r2v); STAGE_W(nb, t+768,  r3v);
      STAGE_W(nb, t+1024, r4v); STAGE_W(nb, t+1280, r5v);
      STAGE_W(nb, t+1536, r6v); STAGE_W(nb, t+1792, r7v);
      if (t < 64) STAGE_W(nb, t+2048, r8v);
    }
    __syncthreads();
  }
  // phase 1: c = tanh(acc+bias) -> LDS Os[b][o], fp16, stride 68
  ushort* Os = (ushort*)Xs;
  const int rg = (l >> 4) * 4;
  #pragma unroll
  for (int tt = 0; tt < 4; ++tt) {
    const int o = tt*16 + (l & 15);
    const float bs = bias[o];
    #pragma unroll
    for (int r = 0; r < 4; ++r) {
      const int b = b0 + rg + r;
      Os[b*68 + o] = f2h(tanhf(acc[tt][r] + bs));
    }
  }
  __syncthreads();
  // phase 2: out = u*h + (1-u)*c, coalesced float4 stores
  {
    const int b = t >> 2, q = t & 3;
    const float* hp = hx + (size_t)b*NU + (size_t)n*Uu + q*16;
    const ushort* up = ubuf + (size_t)b*NU + (size_t)n*Uu + q*16;
    float* op = out + (size_t)b*NU + (size_t)n*Uu + q*16;
    const ushort* os = &Os[b*68 + q*16];
    #pragma unroll
    for (int i = 0; i < 4; ++i) {
      const float4 h4 = *(const float4*)&hp[i*4];
      const uint u01 = *(const uint*)&up[i*4];
      const uint u23 = *(const uint*)&up[i*4 + 2];
      const float u0 = h2f_lo(u01), u1 = h2f_hi(u01), u2 = h2f_lo(u23), u3 = h2f_hi(u23);
      float4 o4;
      o4.x = u0*h4.x + (1.0f - u0)*__half2float(__ushort_as_half(os[i*4+0]));
      o4.y = u1*h4.y + (1.0f - u1)*__half2float(__ushort_as_half(os[i*4+1]));
      o4.z = u2*h4.z + (1.0f - u2)*__half2float(__ushort_as_half(os[i*4+2]));
      o4.w = u3*h4.w + (1.0f - u3)*__half2float(__ushort_as_half(os[i*4+3]));
      *(float4*)&op[i*4] = o4;
    }
  }
}

extern "C" void kernel_launch(void* const* d_in, const int* in_sizes, int n_in,
                              void* d_out, int out_size, void* d_ws, size_t ws_size,
                              hipStream_t stream) {
  const float* inp = (const float*)d_in[0];
  const float* hx  = (const float*)d_in[1];
  const float* sup = (const float*)d_in[2];
  const float* ruW = (const float*)d_in[3];
  const float* ruB = (const float*)d_in[4];
  const float* gW  = (const float*)d_in[5];
  const float* gB  = (const float*)d_in[6];
  float* out = (float*)d_out;

  // workspace: x0 | y1[2] | y2[2] | u | Wpk | ELL(row) | ELL(col) | rcnt  (~214 MB)
  ushort* x0   = (ushort*)d_ws;
  ushort* y1   = x0 + MATSZ;
  ushort* y2   = y1 + 2*MATSZ;
  ushort* ubuf = y2 + 2*MATSZ;
  ushort* Wp1  = ubuf + (size_t)Bb*NU;
  ushort* Wp2  = Wp1 + 61440;
  uint* pkv  = (uint*)(Wp2 + 30720);
  uint* pT   = pkv + (size_t)8192*ELLW;
  int*  rcnt = (int*)(pT + (size_t)8192*ELLW);

  k_fill<<<2048, 256, 0, stream>>>(sup, pkv, rcnt);
  k_tr<<<128, 256, 0, stream>>>(pkv, pT);
  k_wpack<<<360, 256, 0, stream>>>(ruW, gW, Wp1, Wp2);
  k_bx0<<<Nn, 256, 0, stream>>>(inp, hx, x0);

  // gconv1
  k_spmm<false><<<512, 1024, 0, stream>>>(x0, nullptr, y1, rcnt, pT);
  k_spmm<true ><<<512, 1024, 0, stream>>>(y1, x0,      y2, rcnt, pT);
  k_gemm1<<<Nn, 256, 0, stream>>>(x0, y1, y2, Wp1, ruB, hx, x0, ubuf);
  // gconv2 (x0 state slots now hold fp16(r*hx))
  k_spmm<false><<<512, 1024, 0, stream>>>(x0, nullptr, y1, rcnt, pT);
  k_spmm<true ><<<512, 1024, 0, stream>>>(y1, x0,      y2, rcnt, pT);
  k_gemm2<<<Nn, 256, 0, stream>>>(x0, y1, y2, Wp2, gB, hx, ubuf, out);
}